// Round 1
// baseline (1372.341 us; speedup 1.0000x reference)
//
#include <hip/hip_runtime.h>
#include <math.h>

// Problem constants
#define BB 8
#define TT 1024
#define CC 768
#define NH 12
#define HD 64
#define SHH 32
#define SWW 32
#define QSCALE 0.125f   // 64^-0.5

// ---------------------------------------------------------------------------
// Tiled fp32 GEMM: C[M][N] = A[M][K] @ B[K][N] (+ bias[N] if bias != nullptr)
// 64x64 tile, BK=16, 256 threads, 4x4 micro-tile per thread.
// LDS stride 68 keeps b128 reads 16B-aligned and <=2-way bank aliasing.
// ---------------------------------------------------------------------------
__global__ __launch_bounds__(256) void gemm_bias(
    const float* __restrict__ A, const float* __restrict__ B,
    const float* __restrict__ bias, float* __restrict__ C,
    int M, int N, int K)
{
    __shared__ float As[16][68];   // [k][m] (transposed at load)
    __shared__ float Bs[16][68];   // [k][n]

    const int tid = threadIdx.x;
    const int tx = tid & 15, ty = tid >> 4;
    const int m0 = blockIdx.y * 64, n0 = blockIdx.x * 64;

    const int am  = tid >> 2, ak4 = tid & 3;    // A: row am, 4-float k chunk
    const int bk  = tid >> 4, bc4 = tid & 15;   // B: k-row bk, 4-float n chunk

    float acc[4][4] = {{0.f}};

    for (int kt = 0; kt < K; kt += 16) {
        float4 a = *(const float4*)(A + (size_t)(m0 + am) * K + kt + ak4 * 4);
        float4 b = *(const float4*)(B + (size_t)(kt + bk) * N + n0 + bc4 * 4);
        As[ak4*4+0][am] = a.x;
        As[ak4*4+1][am] = a.y;
        As[ak4*4+2][am] = a.z;
        As[ak4*4+3][am] = a.w;
        *(float4*)&Bs[bk][bc4*4] = b;
        __syncthreads();

        #pragma unroll
        for (int k = 0; k < 16; ++k) {
            float4 a4 = *(const float4*)&As[k][ty*4];
            float4 b4 = *(const float4*)&Bs[k][tx*4];
            float av[4] = {a4.x, a4.y, a4.z, a4.w};
            float bv[4] = {b4.x, b4.y, b4.z, b4.w};
            #pragma unroll
            for (int i = 0; i < 4; ++i)
                #pragma unroll
                for (int j = 0; j < 4; ++j)
                    acc[i][j] = fmaf(av[i], bv[j], acc[i][j]);
        }
        __syncthreads();
    }

    #pragma unroll
    for (int i = 0; i < 4; ++i) {
        int m = m0 + ty*4 + i;
        float4 o;
        o.x = acc[i][0]; o.y = acc[i][1]; o.z = acc[i][2]; o.w = acc[i][3];
        if (bias) {
            o.x += bias[n0 + tx*4 + 0];
            o.y += bias[n0 + tx*4 + 1];
            o.z += bias[n0 + tx*4 + 2];
            o.w += bias[n0 + tx*4 + 3];
        }
        *(float4*)(C + (size_t)m * N + n0 + tx*4) = o;
    }
}

// ---------------------------------------------------------------------------
// Flash-style attention with decomposed relative positional bias.
// One block = one (b, h, 64-query tile). 256 threads.
// Q,K stored transposed in LDS ([d][row]) for conflict-free b128 fragment
// reads in the score phase; scores stored transposed ([kj][qi]) so PV reads
// P-fragments contiguously.
// ---------------------------------------------------------------------------
__global__ __launch_bounds__(256) void attn_kernel(
    const float* __restrict__ Q, const float* __restrict__ K,
    const float* __restrict__ V, const float* __restrict__ relh,
    const float* __restrict__ relw, float* __restrict__ O)
{
    __shared__ float sQt[64][68];   // [d][qi]
    __shared__ float sKt[64][68];   // [d][kj]
    __shared__ float sV [64][68];   // [kj][d]
    __shared__ float sSt[64][68];   // [kj][qi]
    __shared__ float sRh[64][32];   // [qi][hk]
    __shared__ float sRw[64][32];   // [qi][wk]
    __shared__ float sM[64], sL[64], sAlpha[64];

    const int tid = threadIdx.x;
    const int bid = blockIdx.x;
    const int qt  = bid & 15;          // query tile 0..15
    const int bh  = bid >> 4;
    const int h   = bh % NH;
    const int b   = bh / NH;
    const size_t base = (size_t)b * TT * CC + (size_t)h * HD;  // + t*CC + d

    // ---- load Q tile transposed
    #pragma unroll
    for (int ii = 0; ii < 4; ++ii) {
        int u  = tid + ii * 256;       // 0..1023 float4 units
        int qi = u >> 4;
        int d4 = u & 15;
        float4 v = *(const float4*)(Q + base + (size_t)(qt*64 + qi) * CC + d4*4);
        sQt[d4*4+0][qi] = v.x;
        sQt[d4*4+1][qi] = v.y;
        sQt[d4*4+2][qi] = v.z;
        sQt[d4*4+3][qi] = v.w;
    }
    if (tid < 64) { sM[tid] = -INFINITY; sL[tid] = 0.f; }
    __syncthreads();

    // ---- rel-pos bias tables: sRh[qi][hk] = q_qi . relh[hq-hk+31]
    #pragma unroll
    for (int ii = 0; ii < 8; ++ii) {
        int e  = tid + ii * 256;       // 0..2047
        int qi = e >> 5, hk = e & 31;
        int hq = qt*2 + (qi >> 5);
        const float* r = relh + (size_t)(hq - hk + 31) * HD;
        float acc = 0.f;
        #pragma unroll 8
        for (int d = 0; d < 64; ++d) acc = fmaf(sQt[d][qi], r[d], acc);
        sRh[qi][hk] = acc;
    }
    #pragma unroll
    for (int ii = 0; ii < 8; ++ii) {
        int e  = tid + ii * 256;
        int qi = e >> 5, wk = e & 31;
        int wq = qi & 31;
        const float* r = relw + (size_t)(wq - wk + 31) * HD;
        float acc = 0.f;
        #pragma unroll 8
        for (int d = 0; d < 64; ++d) acc = fmaf(sQt[d][qi], r[d], acc);
        sRw[qi][wk] = acc;
    }

    const int tx = tid & 15, ty = tid >> 4;
    float o[4][4] = {{0.f}};

    for (int kt = 0; kt < 16; ++kt) {
        // ---- stage K (transposed) and V tiles
        #pragma unroll
        for (int ii = 0; ii < 4; ++ii) {
            int u  = tid + ii * 256;
            int kj = u >> 4;
            int d4 = u & 15;
            float4 kv = *(const float4*)(K + base + (size_t)(kt*64 + kj) * CC + d4*4);
            sKt[d4*4+0][kj] = kv.x;
            sKt[d4*4+1][kj] = kv.y;
            sKt[d4*4+2][kj] = kv.z;
            sKt[d4*4+3][kj] = kv.w;
            float4 vv = *(const float4*)(V + base + (size_t)(kt*64 + kj) * CC + d4*4);
            *(float4*)&sV[kj][d4*4] = vv;
        }
        __syncthreads();   // covers sRh/sRw on first iteration too

        // ---- scores: S[qi][kj] for qi=ty*4+i, kj=tx*4+j
        float s[4][4] = {{0.f}};
        #pragma unroll 16
        for (int d = 0; d < 64; ++d) {
            float4 a4 = *(const float4*)&sQt[d][ty*4];
            float4 b4 = *(const float4*)&sKt[d][tx*4];
            float av[4] = {a4.x, a4.y, a4.z, a4.w};
            float bv[4] = {b4.x, b4.y, b4.z, b4.w};
            #pragma unroll
            for (int i = 0; i < 4; ++i)
                #pragma unroll
                for (int j = 0; j < 4; ++j)
                    s[i][j] = fmaf(av[i], bv[j], s[i][j]);
        }
        #pragma unroll
        for (int j = 0; j < 4; ++j) {
            int kj = tx*4 + j;
            int hk = kt*2 + (kj >> 5);
            int wk = kj & 31;
            float4 col;
            col.x = s[0][j]*QSCALE + sRh[ty*4+0][hk] + sRw[ty*4+0][wk];
            col.y = s[1][j]*QSCALE + sRh[ty*4+1][hk] + sRw[ty*4+1][wk];
            col.z = s[2][j]*QSCALE + sRh[ty*4+2][hk] + sRw[ty*4+2][wk];
            col.w = s[3][j]*QSCALE + sRh[ty*4+3][hk] + sRw[ty*4+3][wk];
            *(float4*)&sSt[kj][ty*4] = col;   // store transposed [kj][qi]
        }
        __syncthreads();

        // ---- online softmax: 4 lanes per query row (adjacent lanes)
        {
            int qi = tid >> 2, c = tid & 3;
            float m_old = sM[qi];
            float sc[16];
            float tmax = -INFINITY;
            #pragma unroll
            for (int kk = 0; kk < 16; ++kk) {
                sc[kk] = sSt[c*16 + kk][qi];
                tmax = fmaxf(tmax, sc[kk]);
            }
            tmax = fmaxf(tmax, __shfl_xor(tmax, 1));
            tmax = fmaxf(tmax, __shfl_xor(tmax, 2));
            float mnew  = fmaxf(m_old, tmax);
            float alpha = expf(m_old - mnew);   // 0 on first tile (m_old=-inf)
            float sum = 0.f;
            #pragma unroll
            for (int kk = 0; kk < 16; ++kk) {
                float p = expf(sc[kk] - mnew);
                sSt[c*16 + kk][qi] = p;
                sum += p;
            }
            sum += __shfl_xor(sum, 1);
            sum += __shfl_xor(sum, 2);
            if (c == 0) {
                sM[qi] = mnew;
                sL[qi] = sL[qi] * alpha + sum;
                sAlpha[qi] = alpha;
            }
        }
        __syncthreads();

        // ---- O = O*alpha + P @ V
        float al[4];
        #pragma unroll
        for (int i = 0; i < 4; ++i) al[i] = sAlpha[ty*4 + i];
        #pragma unroll
        for (int i = 0; i < 4; ++i)
            #pragma unroll
            for (int j = 0; j < 4; ++j)
                o[i][j] *= al[i];
        #pragma unroll 16
        for (int kj = 0; kj < 64; ++kj) {
            float4 p4 = *(const float4*)&sSt[kj][ty*4];
            float4 v4 = *(const float4*)&sV[kj][tx*4];
            float pv[4] = {p4.x, p4.y, p4.z, p4.w};
            float vv[4] = {v4.x, v4.y, v4.z, v4.w};
            #pragma unroll
            for (int i = 0; i < 4; ++i)
                #pragma unroll
                for (int j = 0; j < 4; ++j)
                    o[i][j] = fmaf(pv[i], vv[j], o[i][j]);
        }
        __syncthreads();   // protect sKt/sV/sSt before next tile's staging
    }

    // ---- finalize: divide by l, write (B, T, H*HD)
    float linv[4];
    #pragma unroll
    for (int i = 0; i < 4; ++i) linv[i] = 1.f / sL[ty*4 + i];
    #pragma unroll
    for (int i = 0; i < 4; ++i) {
        int t = qt*64 + ty*4 + i;
        float4 out4;
        out4.x = o[i][0] * linv[i];
        out4.y = o[i][1] * linv[i];
        out4.z = o[i][2] * linv[i];
        out4.w = o[i][3] * linv[i];
        *(float4*)(O + base + (size_t)t * CC + tx*4) = out4;
    }
}

// ---------------------------------------------------------------------------
extern "C" void kernel_launch(void* const* d_in, const int* in_sizes, int n_in,
                              void* d_out, int out_size, void* d_ws, size_t ws_size,
                              hipStream_t stream) {
    const float* x   = (const float*)d_in[0];
    const float* ctx = (const float*)d_in[1];
    const float* Wq  = (const float*)d_in[2];
    const float* Wk  = (const float*)d_in[3];
    const float* Wv  = (const float*)d_in[4];
    const float* Wo  = (const float*)d_in[5];
    const float* bo  = (const float*)d_in[6];
    const float* rh  = (const float*)d_in[7];
    const float* rw  = (const float*)d_in[8];
    float* out = (float*)d_out;

    const size_t MN = (size_t)BB * TT * CC;   // 6291456
    float* Qb = (float*)d_ws;
    float* Kb = Qb + MN;
    float* Vb = Kb + MN;
    float* Ob = Vb + MN;

    dim3 blk(256);
    dim3 gg(CC / 64, (BB * TT) / 64);   // (12, 128)

    hipLaunchKernelGGL(gemm_bias, gg, blk, 0, stream, x,   Wq, (const float*)nullptr, Qb, BB*TT, CC, CC);
    hipLaunchKernelGGL(gemm_bias, gg, blk, 0, stream, ctx, Wk, (const float*)nullptr, Kb, BB*TT, CC, CC);
    hipLaunchKernelGGL(gemm_bias, gg, blk, 0, stream, ctx, Wv, (const float*)nullptr, Vb, BB*TT, CC, CC);

    hipLaunchKernelGGL(attn_kernel, dim3(BB * NH * (TT / 64)), blk, 0, stream,
                       Qb, Kb, Vb, rh, rw, Ob);

    hipLaunchKernelGGL(gemm_bias, gg, blk, 0, stream, Ob, Wo, bo, out, BB*TT, CC, CC);
}

// Round 2
// 897.117 us; speedup vs baseline: 1.5297x; 1.5297x over previous
//
#include <hip/hip_runtime.h>
#include <math.h>

// Problem constants
#define BB 8
#define TT 1024
#define CC 768
#define NH 12
#define HD 64
#define QSCALE 0.125f   // 64^-0.5

typedef __attribute__((ext_vector_type(8))) short short8;   // 8 bf16 (4 VGPRs)
typedef __attribute__((ext_vector_type(4))) short short4v;  // 4 bf16
typedef __attribute__((ext_vector_type(4))) float f32x4;

__device__ inline short f2bf(float f) {
    union { float f; unsigned u; } v; v.f = f;
    unsigned u = v.u;
    u += 0x7fffu + ((u >> 16) & 1u);   // RNE
    return (short)(u >> 16);
}
__device__ inline float bf2f(short s) {
    union { unsigned u; float f; } v;
    v.u = ((unsigned)(unsigned short)s) << 16;
    return v.f;
}

// ---------------------------------------------------------------------------
// Tiled fp32 GEMM (unchanged from round 0): C = A @ B (+bias)
// ---------------------------------------------------------------------------
__global__ __launch_bounds__(256) void gemm_bias(
    const float* __restrict__ A, const float* __restrict__ B,
    const float* __restrict__ bias, float* __restrict__ C,
    int M, int N, int K)
{
    __shared__ float As[16][68];
    __shared__ float Bs[16][68];

    const int tid = threadIdx.x;
    const int tx = tid & 15, ty = tid >> 4;
    const int m0 = blockIdx.y * 64, n0 = blockIdx.x * 64;

    const int am  = tid >> 2, ak4 = tid & 3;
    const int bk  = tid >> 4, bc4 = tid & 15;

    float acc[4][4] = {{0.f}};

    for (int kt = 0; kt < K; kt += 16) {
        float4 a = *(const float4*)(A + (size_t)(m0 + am) * K + kt + ak4 * 4);
        float4 b = *(const float4*)(B + (size_t)(kt + bk) * N + n0 + bc4 * 4);
        As[ak4*4+0][am] = a.x;
        As[ak4*4+1][am] = a.y;
        As[ak4*4+2][am] = a.z;
        As[ak4*4+3][am] = a.w;
        *(float4*)&Bs[bk][bc4*4] = b;
        __syncthreads();

        #pragma unroll
        for (int k = 0; k < 16; ++k) {
            float4 a4 = *(const float4*)&As[k][ty*4];
            float4 b4 = *(const float4*)&Bs[k][tx*4];
            float av[4] = {a4.x, a4.y, a4.z, a4.w};
            float bv[4] = {b4.x, b4.y, b4.z, b4.w};
            #pragma unroll
            for (int i = 0; i < 4; ++i)
                #pragma unroll
                for (int j = 0; j < 4; ++j)
                    acc[i][j] = fmaf(av[i], bv[j], acc[i][j]);
        }
        __syncthreads();
    }

    #pragma unroll
    for (int i = 0; i < 4; ++i) {
        int m = m0 + ty*4 + i;
        float4 o;
        o.x = acc[i][0]; o.y = acc[i][1]; o.z = acc[i][2]; o.w = acc[i][3];
        if (bias) {
            o.x += bias[n0 + tx*4 + 0];
            o.y += bias[n0 + tx*4 + 1];
            o.z += bias[n0 + tx*4 + 2];
            o.w += bias[n0 + tx*4 + 3];
        }
        *(float4*)(C + (size_t)m * N + n0 + tx*4) = o;
    }
}

// ---------------------------------------------------------------------------
// MFMA bf16 flash attention with decomposed rel-pos bias.
// Block = (b, h, 64-query tile), 4 waves; wave w owns q rows w*16..w*16+15.
// QK^T and PV on 16x16x32 bf16 MFMA (fp32 accum); bias/exp/rowsum/O in fp32.
// No max-subtraction (|scores| <~ 2.5). 53 KB LDS -> 2 blocks/CU.
// ---------------------------------------------------------------------------
__global__ __launch_bounds__(256, 2) void attn_mfma(
    const float* __restrict__ Q, const float* __restrict__ K,
    const float* __restrict__ V, const float* __restrict__ relh,
    const float* __restrict__ relw, float* __restrict__ O)
{
    __shared__ short sQ [64][72];     // [qi][d]   bf16, stride 144 B
    __shared__ short sK [64][72];     // [kj][d]
    __shared__ short sVt[64][72];     // [d][kj]   (transposed)
    __shared__ short sP [4][16][72];  // per-wave [qi][kj]
    __shared__ float sRh[64][34];     // [qi][hk]
    __shared__ float sRw[64][34];     // [qi][wk]

    const int tid  = threadIdx.x;
    const int wave = tid >> 6;
    const int lane = tid & 63;
    const int quad = lane >> 4;
    const int l16  = lane & 15;

    const int bid = blockIdx.x;
    const int qt  = bid & 15;
    const int bh  = bid >> 4;
    const int h   = bh % NH;
    const int b   = bh / NH;
    const size_t base = (size_t)b * TT * CC + (size_t)h * HD;

    // ---- stage Q tile (fp32 -> bf16, row-major)
    #pragma unroll
    for (int ii = 0; ii < 4; ++ii) {
        int u = tid + ii * 256;
        int row = u >> 4, d4 = u & 15;
        float4 v = *(const float4*)(Q + base + (size_t)(qt*64 + row) * CC + d4*4);
        short4v s4 = { f2bf(v.x), f2bf(v.y), f2bf(v.z), f2bf(v.w) };
        *(short4v*)&sQ[row][d4*4] = s4;
    }
    __syncthreads();

    // ---- rel-pos bias tables (fp32): sRh[qi][hk] = q_qi . relh[hq-hk+31]
    #pragma unroll
    for (int ii = 0; ii < 8; ++ii) {
        int e = tid + ii * 256;
        int qi = e >> 5, hk = e & 31;
        int hq = qt*2 + (qi >> 5);
        const float* r = relh + (size_t)(hq - hk + 31) * HD;
        float acc = 0.f;
        #pragma unroll 8
        for (int d = 0; d < 64; ++d) acc = fmaf(bf2f(sQ[qi][d]), r[d], acc);
        sRh[qi][hk] = acc;
    }
    #pragma unroll
    for (int ii = 0; ii < 8; ++ii) {
        int e = tid + ii * 256;
        int qi = e >> 5, wk = e & 31;
        int wq = qi & 31;
        const float* r = relw + (size_t)(wq - wk + 31) * HD;
        float acc = 0.f;
        #pragma unroll 8
        for (int d = 0; d < 64; ++d) acc = fmaf(bf2f(sQ[qi][d]), r[d], acc);
        sRw[qi][wk] = acc;
    }
    // (sRh/sRw writes are covered by the first __syncthreads in the kt loop)

    // ---- A-fragments of Q (persistent): A[m=l16][k=quad*8+j]
    const int qrow = wave*16 + l16;
    short8 aQ0 = *(const short8*)&sQ[qrow][quad*8];
    short8 aQ1 = *(const short8*)&sQ[qrow][32 + quad*8];

    f32x4 o[4] = {{0.f,0.f,0.f,0.f},{0.f,0.f,0.f,0.f},
                  {0.f,0.f,0.f,0.f},{0.f,0.f,0.f,0.f}};
    float l[4] = {0.f, 0.f, 0.f, 0.f};

    for (int kt = 0; kt < 16; ++kt) {
        // ---- stage K (row-major) and V (transposed) as bf16
        #pragma unroll
        for (int ii = 0; ii < 4; ++ii) {
            int u = tid + ii * 256;
            int kj = u >> 4, d4 = u & 15;
            float4 kv = *(const float4*)(K + base + (size_t)(kt*64 + kj) * CC + d4*4);
            short4v s4 = { f2bf(kv.x), f2bf(kv.y), f2bf(kv.z), f2bf(kv.w) };
            *(short4v*)&sK[kj][d4*4] = s4;
            float4 vv = *(const float4*)(V + base + (size_t)(kt*64 + kj) * CC + d4*4);
            sVt[d4*4+0][kj] = f2bf(vv.x);
            sVt[d4*4+1][kj] = f2bf(vv.y);
            sVt[d4*4+2][kj] = f2bf(vv.z);
            sVt[d4*4+3][kj] = f2bf(vv.w);
        }
        __syncthreads();

        // ---- scores 16q x 64k per wave: 8 MFMA; then bias + exp + pack
        float rs[4] = {0.f, 0.f, 0.f, 0.f};
        #pragma unroll
        for (int bb = 0; bb < 4; ++bb) {
            short8 bK0 = *(const short8*)&sK[bb*16 + l16][quad*8];
            short8 bK1 = *(const short8*)&sK[bb*16 + l16][32 + quad*8];
            f32x4 c = {0.f, 0.f, 0.f, 0.f};
            c = __builtin_amdgcn_mfma_f32_16x16x32_bf16(aQ0, bK0, c, 0, 0, 0);
            c = __builtin_amdgcn_mfma_f32_16x16x32_bf16(aQ1, bK1, c, 0, 0, 0);
            const int hk = kt*2 + (bb >> 1);
            const int wk = ((bb & 1) << 4) + l16;
            #pragma unroll
            for (int r = 0; r < 4; ++r) {
                int qi = wave*16 + quad*4 + r;
                float p = __expf(c[r]*QSCALE + sRh[qi][hk] + sRw[qi][wk]);
                rs[r] += p;
                sP[wave][quad*4 + r][bb*16 + l16] = f2bf(p);
            }
        }
        // ---- row sums: reduce over the 16 lanes of this quad
        #pragma unroll
        for (int r = 0; r < 4; ++r) {
            float t = rs[r];
            t += __shfl_xor(t, 1);
            t += __shfl_xor(t, 2);
            t += __shfl_xor(t, 4);
            t += __shfl_xor(t, 8);
            l[r] += t;
        }
        // ---- PV: O[16q][64d] += P @ V   (8 MFMA, wave-private sP)
        short8 aP0 = *(const short8*)&sP[wave][l16][quad*8];
        short8 aP1 = *(const short8*)&sP[wave][l16][32 + quad*8];
        #pragma unroll
        for (int n = 0; n < 4; ++n) {
            short8 bV0 = *(const short8*)&sVt[n*16 + l16][quad*8];
            short8 bV1 = *(const short8*)&sVt[n*16 + l16][32 + quad*8];
            o[n] = __builtin_amdgcn_mfma_f32_16x16x32_bf16(aP0, bV0, o[n], 0, 0, 0);
            o[n] = __builtin_amdgcn_mfma_f32_16x16x32_bf16(aP1, bV1, o[n], 0, 0, 0);
        }
        __syncthreads();   // before next tile's staging overwrites sK/sVt
    }

    // ---- finalize: /l, store (B,T,C) at head offset
    float inv[4];
    #pragma unroll
    for (int r = 0; r < 4; ++r) inv[r] = 1.f / l[r];
    #pragma unroll
    for (int n = 0; n < 4; ++n)
        #pragma unroll
        for (int r = 0; r < 4; ++r) {
            int t = qt*64 + wave*16 + quad*4 + r;
            O[base + (size_t)t * CC + n*16 + l16] = o[n][r] * inv[r];
        }
}

// ---------------------------------------------------------------------------
extern "C" void kernel_launch(void* const* d_in, const int* in_sizes, int n_in,
                              void* d_out, int out_size, void* d_ws, size_t ws_size,
                              hipStream_t stream) {
    const float* x   = (const float*)d_in[0];
    const float* ctx = (const float*)d_in[1];
    const float* Wq  = (const float*)d_in[2];
    const float* Wk  = (const float*)d_in[3];
    const float* Wv  = (const float*)d_in[4];
    const float* Wo  = (const float*)d_in[5];
    const float* bo  = (const float*)d_in[6];
    const float* rh  = (const float*)d_in[7];
    const float* rw  = (const float*)d_in[8];
    float* out = (float*)d_out;

    const size_t MN = (size_t)BB * TT * CC;
    float* Qb = (float*)d_ws;
    float* Kb = Qb + MN;
    float* Vb = Kb + MN;
    float* Ob = Vb + MN;

    dim3 blk(256);
    dim3 gg(CC / 64, (BB * TT) / 64);

    hipLaunchKernelGGL(gemm_bias, gg, blk, 0, stream, x,   Wq, (const float*)nullptr, Qb, BB*TT, CC, CC);
    hipLaunchKernelGGL(gemm_bias, gg, blk, 0, stream, ctx, Wk, (const float*)nullptr, Kb, BB*TT, CC, CC);
    hipLaunchKernelGGL(gemm_bias, gg, blk, 0, stream, ctx, Wv, (const float*)nullptr, Vb, BB*TT, CC, CC);

    hipLaunchKernelGGL(attn_mfma, dim3(BB * NH * (TT / 64)), blk, 0, stream,
                       Qb, Kb, Vb, rh, rw, Ob);

    hipLaunchKernelGGL(gemm_bias, gg, blk, 0, stream, Ob, Wo, bo, out, BB*TT, CC, CC);
}

// Round 4
// 337.421 us; speedup vs baseline: 4.0672x; 2.6587x over previous
//
#include <hip/hip_runtime.h>
#include <math.h>

#define BB 8
#define TT 1024
#define CC 768
#define NH 12
#define HD 64

typedef __attribute__((ext_vector_type(8))) short short8;   // 8 bf16
typedef __attribute__((ext_vector_type(4))) short short4v;  // 4 bf16
typedef __attribute__((ext_vector_type(4))) float f32x4;

__device__ inline short f2bf(float f) {
    union { float f; unsigned u; } v; v.f = f;
    unsigned u = v.u;
    u += 0x7fffu + ((u >> 16) & 1u);   // RNE
    return (short)(u >> 16);
}
__device__ inline float bf2f(short s) {
    union { unsigned u; float f; } v;
    v.u = ((unsigned)(unsigned short)s) << 16;
    return v.f;
}

// ---------------------------------------------------------------------------
// fp32 -> bf16 elementwise convert (n multiple of 4)
// ---------------------------------------------------------------------------
__global__ __launch_bounds__(256) void convert_bf16(
    const float* __restrict__ in, short* __restrict__ out, int n)
{
    int i = (blockIdx.x * 256 + threadIdx.x) * 4;
    if (i < n) {
        float4 v = *(const float4*)(in + i);
        short4v s = { f2bf(v.x), f2bf(v.y), f2bf(v.z), f2bf(v.w) };
        *(short4v*)(out + i) = s;
    }
}

// ---------------------------------------------------------------------------
// 768x768 weight transpose + bf16 convert: WT[n][k] = W[k][n].
// Optionally also emits the bf16 residual (lo) for split-precision GEMM.
// ---------------------------------------------------------------------------
__global__ __launch_bounds__(256) void transpose_w(
    const float* __restrict__ W, short* __restrict__ WT,
    short* __restrict__ WTlo)
{
    __shared__ float tile[64][65];
    const int tx = threadIdx.x & 15, ty = threadIdx.x >> 4;
    const int n0 = blockIdx.x * 64, k0 = blockIdx.y * 64;

    #pragma unroll
    for (int ii = 0; ii < 4; ++ii) {
        int k = ty + ii * 16;
        float4 v = *(const float4*)(W + (size_t)(k0 + k) * CC + n0 + tx * 4);
        tile[k][tx*4+0] = v.x; tile[k][tx*4+1] = v.y;
        tile[k][tx*4+2] = v.z; tile[k][tx*4+3] = v.w;
    }
    __syncthreads();
    #pragma unroll
    for (int ii = 0; ii < 4; ++ii) {
        int n = ty + ii * 16;
        float w0 = tile[tx*4+0][n], w1 = tile[tx*4+1][n];
        float w2 = tile[tx*4+2][n], w3 = tile[tx*4+3][n];
        short4v hi = { f2bf(w0), f2bf(w1), f2bf(w2), f2bf(w3) };
        *(short4v*)(WT + (size_t)(n0 + n) * CC + k0 + tx * 4) = hi;
        if (WTlo) {
            short4v lo = { f2bf(w0 - bf2f(hi.x)), f2bf(w1 - bf2f(hi.y)),
                           f2bf(w2 - bf2f(hi.z)), f2bf(w3 - bf2f(hi.w)) };
            *(short4v*)(WTlo + (size_t)(n0 + n) * CC + k0 + tx * 4) = lo;
        }
    }
}

// ---------------------------------------------------------------------------
// bf16 MFMA NT-GEMM: C[m][n] = scale * sum_k A[m][k] * BT[n][k]
// M x N, K=768, 128x128 tile, BK=64, 256 threads (4 waves, 2x2 of 64x64).
// Output written bf16 into head-major [b, h, t, d] layout (m=b*1024+t,
// n=h*64+d).  LDS 36.9 KB -> 4 blocks/CU.
// ---------------------------------------------------------------------------
__global__ __launch_bounds__(256) void gemm_qkv(
    const short* __restrict__ A, const short* __restrict__ BT,
    short* __restrict__ Chead, float scale)
{
    __shared__ short sA[128][72];
    __shared__ short sB[128][72];

    const int tid  = threadIdx.x;
    const int wave = tid >> 6, lane = tid & 63;
    const int quad = lane >> 4, l16 = lane & 15;
    const int m0 = blockIdx.y * 128, n0 = blockIdx.x * 128;
    const int mw = (wave & 1) * 64, nw = (wave >> 1) * 64;

    f32x4 acc[4][4];
    #pragma unroll
    for (int i = 0; i < 4; ++i)
        #pragma unroll
        for (int j = 0; j < 4; ++j) acc[i][j] = (f32x4){0.f,0.f,0.f,0.f};

    for (int kt = 0; kt < CC; kt += 64) {
        #pragma unroll
        for (int ii = 0; ii < 4; ++ii) {
            int u = tid + ii * 256;            // 0..1023
            int row = u >> 3, c8 = u & 7;
            short8 a = *(const short8*)(A  + (size_t)(m0 + row) * CC + kt + c8 * 8);
            *(short8*)&sA[row][c8 * 8] = a;
            short8 b = *(const short8*)(BT + (size_t)(n0 + row) * CC + kt + c8 * 8);
            *(short8*)&sB[row][c8 * 8] = b;
        }
        __syncthreads();
        #pragma unroll
        for (int kk = 0; kk < 2; ++kk) {
            short8 af[4], bf[4];
            #pragma unroll
            for (int mi = 0; mi < 4; ++mi)
                af[mi] = *(const short8*)&sA[mw + mi*16 + l16][kk*32 + quad*8];
            #pragma unroll
            for (int nj = 0; nj < 4; ++nj)
                bf[nj] = *(const short8*)&sB[nw + nj*16 + l16][kk*32 + quad*8];
            #pragma unroll
            for (int mi = 0; mi < 4; ++mi)
                #pragma unroll
                for (int nj = 0; nj < 4; ++nj)
                    acc[mi][nj] = __builtin_amdgcn_mfma_f32_16x16x32_bf16(
                        af[mi], bf[nj], acc[mi][nj], 0, 0, 0);
        }
        __syncthreads();
    }

    #pragma unroll
    for (int mi = 0; mi < 4; ++mi)
        #pragma unroll
        for (int nj = 0; nj < 4; ++nj)
            #pragma unroll
            for (int r = 0; r < 4; ++r) {
                int gm = m0 + mw + mi*16 + quad*4 + r;
                int gn = n0 + nw + nj*16 + l16;
                int bI = gm >> 10, tI = gm & 1023;
                int hI = gn >> 6,  dI = gn & 63;
                Chead[(((size_t)bI * NH + hI) * TT + tI) * HD + dI] =
                    f2bf(acc[mi][nj][r] * scale);
            }
}

// ---------------------------------------------------------------------------
// Split-precision output GEMM: out = Ahi@Bhi + Ahi@Blo + Alo@Bhi + bias
// (fp32 out).  A is [8192][768] bf16 hi/lo; BT hi/lo are [768][768] bf16.
// LDS 73.7 KB -> 2 blocks/CU.
// ---------------------------------------------------------------------------
__global__ __launch_bounds__(256, 2) void gemm_out3(
    const short* __restrict__ Ah, const short* __restrict__ Al,
    const short* __restrict__ Bh, const short* __restrict__ Bl,
    const float* __restrict__ bias, float* __restrict__ out)
{
    __shared__ short sAh[128][72];
    __shared__ short sAl[128][72];
    __shared__ short sBh[128][72];
    __shared__ short sBl[128][72];

    const int tid  = threadIdx.x;
    const int wave = tid >> 6, lane = tid & 63;
    const int quad = lane >> 4, l16 = lane & 15;
    const int m0 = blockIdx.y * 128, n0 = blockIdx.x * 128;
    const int mw = (wave & 1) * 64, nw = (wave >> 1) * 64;

    f32x4 acc[4][4];
    #pragma unroll
    for (int i = 0; i < 4; ++i)
        #pragma unroll
        for (int j = 0; j < 4; ++j) acc[i][j] = (f32x4){0.f,0.f,0.f,0.f};

    for (int kt = 0; kt < CC; kt += 64) {
        #pragma unroll
        for (int ii = 0; ii < 4; ++ii) {
            int u = tid + ii * 256;
            int row = u >> 3, c8 = u & 7;
            size_t ao = (size_t)(m0 + row) * CC + kt + c8 * 8;
            size_t bo = (size_t)(n0 + row) * CC + kt + c8 * 8;
            *(short8*)&sAh[row][c8*8] = *(const short8*)(Ah + ao);
            *(short8*)&sAl[row][c8*8] = *(const short8*)(Al + ao);
            *(short8*)&sBh[row][c8*8] = *(const short8*)(Bh + bo);
            *(short8*)&sBl[row][c8*8] = *(const short8*)(Bl + bo);
        }
        __syncthreads();
        #pragma unroll
        for (int kk = 0; kk < 2; ++kk) {
            short8 ah[4], al[4], bh[4], bl[4];
            #pragma unroll
            for (int mi = 0; mi < 4; ++mi) {
                ah[mi] = *(const short8*)&sAh[mw + mi*16 + l16][kk*32 + quad*8];
                al[mi] = *(const short8*)&sAl[mw + mi*16 + l16][kk*32 + quad*8];
            }
            #pragma unroll
            for (int nj = 0; nj < 4; ++nj) {
                bh[nj] = *(const short8*)&sBh[nw + nj*16 + l16][kk*32 + quad*8];
                bl[nj] = *(const short8*)&sBl[nw + nj*16 + l16][kk*32 + quad*8];
            }
            #pragma unroll
            for (int mi = 0; mi < 4; ++mi)
                #pragma unroll
                for (int nj = 0; nj < 4; ++nj) {
                    acc[mi][nj] = __builtin_amdgcn_mfma_f32_16x16x32_bf16(
                        ah[mi], bh[nj], acc[mi][nj], 0, 0, 0);
                    acc[mi][nj] = __builtin_amdgcn_mfma_f32_16x16x32_bf16(
                        ah[mi], bl[nj], acc[mi][nj], 0, 0, 0);
                    acc[mi][nj] = __builtin_amdgcn_mfma_f32_16x16x32_bf16(
                        al[mi], bh[nj], acc[mi][nj], 0, 0, 0);
                }
        }
        __syncthreads();
    }

    #pragma unroll
    for (int mi = 0; mi < 4; ++mi)
        #pragma unroll
        for (int nj = 0; nj < 4; ++nj)
            #pragma unroll
            for (int r = 0; r < 4; ++r) {
                int gm = m0 + mw + mi*16 + quad*4 + r;
                int gn = n0 + nw + nj*16 + l16;
                out[(size_t)gm * CC + gn] = acc[mi][nj][r] + bias[gn];
            }
}

// ---------------------------------------------------------------------------
// MFMA bf16 flash attention, rel-pos bias via MFMA.
// Block = (b, h, 64-q tile), 4 waves; wave owns 16 q rows.  K comes in
// pre-scaled by 2^-3.  Output = bf16 hi+lo into [b, t, C].
// LDS ~41 KB -> 3 blocks/CU.
// ---------------------------------------------------------------------------
__global__ __launch_bounds__(256) void attn_mfma(
    const short* __restrict__ Q, const short* __restrict__ K,
    const short* __restrict__ V, const float* __restrict__ relh,
    const float* __restrict__ relw,
    short* __restrict__ Ohi, short* __restrict__ Olo)
{
    __shared__ short sK [64][72];    // k-loop: K tile | prologue: relh window (33 rows)
    __shared__ short sVt[64][72];    // k-loop: V^T    | prologue: relw rows 0..63
    __shared__ short sP [4][16][72]; // k-loop: per-wave P | prologue: Q tile [64][72]
    __shared__ short sH [64][36];    // rh table [qi][hk] bf16
    __shared__ short sG [64][68];    // G = Q @ relw^T window, bf16

    const int tid  = threadIdx.x;
    const int wave = tid >> 6, lane = tid & 63;
    const int quad = lane >> 4, l16 = lane & 15;

    const int bid = blockIdx.x;
    const int qt  = bid & 15;
    const int bh  = bid >> 4;
    const int h   = bh % NH;
    const int b   = bh / NH;
    const size_t hbase = ((size_t)b * NH + h) * TT * HD;

    short* sQ = &sP[0][0][0];        // [64][72] overlay

    // ---- prologue staging: Q tile (bf16 direct), relh window, relw table
    #pragma unroll
    for (int ii = 0; ii < 2; ++ii) {
        int u = tid + ii * 256;      // 0..511
        int row = u >> 3, c8 = u & 7;
        short8 v = *(const short8*)(Q + hbase + (size_t)(qt*64 + row) * HD + c8*8);
        *(short8*)&sQ[row*72 + c8*8] = v;
    }
    #pragma unroll
    for (int ii = 0; ii < 2; ++ii) {
        int u = tid + ii * 256;
        if (u < 264) {               // 33 rows x 8 chunks
            int row = u >> 3, c8 = u & 7;
            const float* src = relh + (size_t)(2*qt + row) * HD + c8*8;
            float4 v0 = *(const float4*)(src);
            float4 v1 = *(const float4*)(src + 4);
            short8 s = { f2bf(v0.x), f2bf(v0.y), f2bf(v0.z), f2bf(v0.w),
                         f2bf(v1.x), f2bf(v1.y), f2bf(v1.z), f2bf(v1.w) };
            *(short8*)&sK[row][c8*8] = s;
        }
    }
    #pragma unroll
    for (int ii = 0; ii < 2; ++ii) {
        int u = tid + ii * 256;      // 0..511 : 64 rows (row 63 = dup of 62)
        int row = u >> 3, c8 = u & 7;
        int sr = row < 63 ? row : 62;
        const float* src = relw + (size_t)sr * HD + c8*8;
        float4 v0 = *(const float4*)(src);
        float4 v1 = *(const float4*)(src + 4);
        short8 s = { f2bf(v0.x), f2bf(v0.y), f2bf(v0.z), f2bf(v0.w),
                     f2bf(v1.x), f2bf(v1.y), f2bf(v1.z), f2bf(v1.w) };
        *(short8*)&sVt[row][c8*8] = s;
    }
    __syncthreads();

    // ---- persistent Q A-fragments
    const int qrow = wave*16 + l16;
    short8 aQ0 = *(const short8*)&sQ[qrow*72 + quad*8];
    short8 aQ1 = *(const short8*)&sQ[qrow*72 + 32 + quad*8];

    // ---- RH bias via MFMA: C[qi'][hk] = q . relh[hq-hk+31]; hq wave-uniform
    const int hqLoc = wave >> 1;
    #pragma unroll
    for (int t = 0; t < 2; ++t) {
        int wr = hqLoc + 31 - (t*16 + l16);          // window row, in [0,32]
        short8 b0 = *(const short8*)&sK[wr][quad*8];
        short8 b1 = *(const short8*)&sK[wr][32 + quad*8];
        f32x4 c = {0.f,0.f,0.f,0.f};
        c = __builtin_amdgcn_mfma_f32_16x16x32_bf16(aQ0, b0, c, 0, 0, 0);
        c = __builtin_amdgcn_mfma_f32_16x16x32_bf16(aQ1, b1, c, 0, 0, 0);
        #pragma unroll
        for (int r = 0; r < 4; ++r)
            sH[wave*16 + quad*4 + r][t*16 + l16] = f2bf(c[r]);
    }
    // ---- G = Q @ relw^T (cols n' = 0..63; col 63 garbage, never gathered)
    #pragma unroll
    for (int t = 0; t < 4; ++t) {
        short8 b0 = *(const short8*)&sVt[t*16 + l16][quad*8];
        short8 b1 = *(const short8*)&sVt[t*16 + l16][32 + quad*8];
        f32x4 c = {0.f,0.f,0.f,0.f};
        c = __builtin_amdgcn_mfma_f32_16x16x32_bf16(aQ0, b0, c, 0, 0, 0);
        c = __builtin_amdgcn_mfma_f32_16x16x32_bf16(aQ1, b1, c, 0, 0, 0);
        #pragma unroll
        for (int r = 0; r < 4; ++r)
            sG[wave*16 + quad*4 + r][t*16 + l16] = f2bf(c[r]);
    }
    __syncthreads();

    // ---- gather per-lane RW bias into registers: rw[qi][wk]=G[qi][wq-wk+31]
    float rwReg[2][4];
    #pragma unroll
    for (int j = 0; j < 2; ++j)
        #pragma unroll
        for (int r = 0; r < 4; ++r) {
            int idx = (wave&1)*16 + quad*4 + r - j*16 - l16 + 31;  // 0..62
            rwReg[j][r] = bf2f(sG[wave*16 + quad*4 + r][idx]);
        }

    f32x4 o[4] = {{0.f,0.f,0.f,0.f},{0.f,0.f,0.f,0.f},
                  {0.f,0.f,0.f,0.f},{0.f,0.f,0.f,0.f}};
    float l[4] = {0.f,0.f,0.f,0.f};

    for (int kt = 0; kt < 16; ++kt) {
        // ---- stage K tile (row-major) and V tile (transposed), bf16 direct
        #pragma unroll
        for (int ii = 0; ii < 2; ++ii) {
            int u = tid + ii * 256;
            int row = u >> 3, c8 = u & 7;
            short8 kv = *(const short8*)(K + hbase + (size_t)(kt*64 + row) * HD + c8*8);
            *(short8*)&sK[row][c8*8] = kv;
            short8 vv = *(const short8*)(V + hbase + (size_t)(kt*64 + row) * HD + c8*8);
            #pragma unroll
            for (int j = 0; j < 8; ++j) sVt[c8*8 + j][row] = vv[j];
        }
        __syncthreads();

        // ---- per-row RH bias for this k-tile (broadcast u16 LDS reads)
        float rh[2][4];
        #pragma unroll
        for (int t2 = 0; t2 < 2; ++t2)
            #pragma unroll
            for (int r = 0; r < 4; ++r)
                rh[t2][r] = bf2f(sH[wave*16 + quad*4 + r][kt*2 + t2]);

        // ---- scores + exp + pack P
        float rs[4] = {0.f,0.f,0.f,0.f};
        #pragma unroll
        for (int bb = 0; bb < 4; ++bb) {
            short8 bK0 = *(const short8*)&sK[(bb*16 + l16)][quad*8];
            short8 bK1 = *(const short8*)&sK[(bb*16 + l16)][32 + quad*8];
            f32x4 c = {0.f,0.f,0.f,0.f};
            c = __builtin_amdgcn_mfma_f32_16x16x32_bf16(aQ0, bK0, c, 0, 0, 0);
            c = __builtin_amdgcn_mfma_f32_16x16x32_bf16(aQ1, bK1, c, 0, 0, 0);
            #pragma unroll
            for (int r = 0; r < 4; ++r) {
                float p = __expf(c[r] + rh[bb>>1][r] + rwReg[bb&1][r]);
                rs[r] += p;
                sP[wave][quad*4 + r][bb*16 + l16] = f2bf(p);
            }
        }
        #pragma unroll
        for (int r = 0; r < 4; ++r) {
            float t = rs[r];
            t += __shfl_xor(t, 1);
            t += __shfl_xor(t, 2);
            t += __shfl_xor(t, 4);
            t += __shfl_xor(t, 8);
            l[r] += t;
        }

        // ---- O += P @ V
        short8 aP0 = *(const short8*)&sP[wave][l16][quad*8];
        short8 aP1 = *(const short8*)&sP[wave][l16][32 + quad*8];
        #pragma unroll
        for (int n = 0; n < 4; ++n) {
            short8 bV0 = *(const short8*)&sVt[n*16 + l16][quad*8];
            short8 bV1 = *(const short8*)&sVt[n*16 + l16][32 + quad*8];
            o[n] = __builtin_amdgcn_mfma_f32_16x16x32_bf16(aP0, bV0, o[n], 0, 0, 0);
            o[n] = __builtin_amdgcn_mfma_f32_16x16x32_bf16(aP1, bV1, o[n], 0, 0, 0);
        }
        __syncthreads();
    }

    // ---- finalize: /l, emit bf16 hi + lo into [b, t, C]
    float inv[4];
    #pragma unroll
    for (int r = 0; r < 4; ++r) inv[r] = 1.f / l[r];
    #pragma unroll
    for (int n = 0; n < 4; ++n)
        #pragma unroll
        for (int r = 0; r < 4; ++r) {
            int t = qt*64 + wave*16 + quad*4 + r;
            float val = o[n][r] * inv[r];
            short hi = f2bf(val);
            short lo = f2bf(val - bf2f(hi));
            size_t addr = ((size_t)b * TT + t) * CC + h*HD + n*16 + l16;
            Ohi[addr] = hi;
            Olo[addr] = lo;
        }
}

// ---------------------------------------------------------------------------
extern "C" void kernel_launch(void* const* d_in, const int* in_sizes, int n_in,
                              void* d_out, int out_size, void* d_ws, size_t ws_size,
                              hipStream_t stream) {
    const float* x   = (const float*)d_in[0];
    const float* ctx = (const float*)d_in[1];
    const float* Wq  = (const float*)d_in[2];
    const float* Wk  = (const float*)d_in[3];
    const float* Wv  = (const float*)d_in[4];
    const float* Wo  = (const float*)d_in[5];
    const float* bo  = (const float*)d_in[6];
    const float* rh  = (const float*)d_in[7];
    const float* rw  = (const float*)d_in[8];
    float* out = (float*)d_out;

    const size_t MN = (size_t)BB * TT * CC;   // 6291456
    const size_t WN = (size_t)CC * CC;        // 589824
    short* p = (short*)d_ws;
    short* xbf  = p; p += MN;
    short* cbf  = p; p += MN;
    short* WqT  = p; p += WN;
    short* WkT  = p; p += WN;
    short* WvT  = p; p += WN;
    short* WoTh = p; p += WN;
    short* WoTl = p; p += WN;
    short* Qh   = p; p += MN;
    short* Kh   = p; p += MN;
    short* Vh   = p; p += MN;
    short* Oh   = p; p += MN;
    short* Ol   = p; p += MN;

    dim3 blk(256);

    convert_bf16<<<dim3(MN/1024), blk, 0, stream>>>(x,   xbf, (int)MN);
    convert_bf16<<<dim3(MN/1024), blk, 0, stream>>>(ctx, cbf, (int)MN);

    dim3 gt(12, 12);
    transpose_w<<<gt, blk, 0, stream>>>(Wq, WqT, (short*)nullptr);
    transpose_w<<<gt, blk, 0, stream>>>(Wk, WkT, (short*)nullptr);
    transpose_w<<<gt, blk, 0, stream>>>(Wv, WvT, (short*)nullptr);
    transpose_w<<<gt, blk, 0, stream>>>(Wo, WoTh, WoTl);

    dim3 gg(CC/128, (BB*TT)/128);   // (6, 64)
    gemm_qkv<<<gg, blk, 0, stream>>>(xbf, WqT, Qh, 1.0f);
    gemm_qkv<<<gg, blk, 0, stream>>>(cbf, WkT, Kh, 0.125f);  // fold score scale into K
    gemm_qkv<<<gg, blk, 0, stream>>>(cbf, WvT, Vh, 1.0f);

    attn_mfma<<<dim3(BB*NH*(TT/64)), blk, 0, stream>>>(Qh, Kh, Vh, rh, rw, Oh, Ol);

    gemm_out3<<<gg, blk, 0, stream>>>(Oh, Ol, WoTh, WoTl, bo, out);
}

// Round 5
// 304.031 us; speedup vs baseline: 4.5138x; 1.1098x over previous
//
#include <hip/hip_runtime.h>
#include <math.h>

#define BB 8
#define TT 1024
#define CC 768
#define NH 12
#define HD 64

typedef __attribute__((ext_vector_type(8))) _Float16 hv8;   // 8 fp16 (4 VGPRs)
typedef __attribute__((ext_vector_type(8))) short  short8;  // raw 16B
typedef __attribute__((ext_vector_type(4))) float  f32x4;

// ---------------------------------------------------------------------------
// fp32 -> fp16 convert, 8 elements/thread
// ---------------------------------------------------------------------------
__global__ __launch_bounds__(256) void convert_f16(
    const float* __restrict__ in, _Float16* __restrict__ out, int n)
{
    int i = (blockIdx.x * 256 + threadIdx.x) * 8;
    if (i < n) {
        float4 v0 = *(const float4*)(in + i);
        float4 v1 = *(const float4*)(in + i + 4);
        hv8 h = { (_Float16)v0.x, (_Float16)v0.y, (_Float16)v0.z, (_Float16)v0.w,
                  (_Float16)v1.x, (_Float16)v1.y, (_Float16)v1.z, (_Float16)v1.w };
        *(hv8*)(out + i) = h;
    }
}

// ---------------------------------------------------------------------------
// 768x768 weight transpose + fp16 convert: WT[n][k] = W[k][n]
// ---------------------------------------------------------------------------
__global__ __launch_bounds__(256) void transpose_w(
    const float* __restrict__ W, _Float16* __restrict__ WT)
{
    __shared__ float tile[64][65];
    const int tx = threadIdx.x & 15, ty = threadIdx.x >> 4;
    const int n0 = blockIdx.x * 64, k0 = blockIdx.y * 64;

    #pragma unroll
    for (int ii = 0; ii < 4; ++ii) {
        int k = ty + ii * 16;
        float4 v = *(const float4*)(W + (size_t)(k0 + k) * CC + n0 + tx * 4);
        tile[k][tx*4+0] = v.x; tile[k][tx*4+1] = v.y;
        tile[k][tx*4+2] = v.z; tile[k][tx*4+3] = v.w;
    }
    __syncthreads();
    #pragma unroll
    for (int ii = 0; ii < 4; ++ii) {
        int n = ty + ii * 16;
        _Float16 h0 = (_Float16)tile[tx*4+0][n];
        _Float16 h1 = (_Float16)tile[tx*4+1][n];
        _Float16 h2 = (_Float16)tile[tx*4+2][n];
        _Float16 h3 = (_Float16)tile[tx*4+3][n];
        _Float16* dst = WT + (size_t)(n0 + n) * CC + k0 + tx * 4;
        dst[0] = h0; dst[1] = h1; dst[2] = h2; dst[3] = h3;
    }
}

// ---------------------------------------------------------------------------
// Per-head V transpose: Vh [b,h,t,d] -> Vt [b,h,d,t]  (fp16)
// One block per (bh, 64-t tile).  LDS-conflict-free gather; 16B scattered
// global stores are absorbed/merged by L2.
// ---------------------------------------------------------------------------
__global__ __launch_bounds__(256) void vtrans(
    const _Float16* __restrict__ Vh, _Float16* __restrict__ Vt)
{
    __shared__ _Float16 tile[64][80];
    const int tid = threadIdx.x;
    const int bh = blockIdx.y;
    const int t0 = blockIdx.x * 64;
    const size_t base = (size_t)bh * TT * HD;

    #pragma unroll
    for (int ii = 0; ii < 2; ++ii) {
        int u = tid + ii * 256;
        int row = u >> 3, c8 = u & 7;
        *(short8*)&tile[row][c8*8] =
            *(const short8*)(Vh + base + (size_t)(t0 + row) * HD + c8*8);
    }
    __syncthreads();
    #pragma unroll
    for (int ii = 0; ii < 2; ++ii) {
        int u = tid + ii * 256;
        int tc8 = u >> 6, d = u & 63;   // lanes sweep d -> conflict-free LDS
        hv8 o;
        #pragma unroll
        for (int j = 0; j < 8; ++j) o[j] = tile[tc8*8 + j][d];
        *(hv8*)(Vt + base + (size_t)d * TT + t0 + tc8*8) = o;
    }
}

// ---------------------------------------------------------------------------
// fp16 MFMA NT-GEMM: C[m][n] = scale * sum_k A[m][k] * BT[n][k]
// 128x128 tile, BK=64, 4 waves.  Output fp16 head-major [b,h,t,d].
// ---------------------------------------------------------------------------
__global__ __launch_bounds__(256) void gemm_qkv(
    const _Float16* __restrict__ A, const _Float16* __restrict__ BT,
    _Float16* __restrict__ Chead, float scale)
{
    __shared__ _Float16 sA[128][72];
    __shared__ _Float16 sB[128][72];

    const int tid  = threadIdx.x;
    const int wave = tid >> 6, lane = tid & 63;
    const int quad = lane >> 4, l16 = lane & 15;
    const int m0 = blockIdx.y * 128, n0 = blockIdx.x * 128;
    const int mw = (wave & 1) * 64, nw = (wave >> 1) * 64;

    f32x4 acc[4][4];
    #pragma unroll
    for (int i = 0; i < 4; ++i)
        #pragma unroll
        for (int j = 0; j < 4; ++j) acc[i][j] = (f32x4){0.f,0.f,0.f,0.f};

    for (int kt = 0; kt < CC; kt += 64) {
        #pragma unroll
        for (int ii = 0; ii < 4; ++ii) {
            int u = tid + ii * 256;
            int row = u >> 3, c8 = u & 7;
            *(short8*)&sA[row][c8*8] =
                *(const short8*)(A  + (size_t)(m0 + row) * CC + kt + c8*8);
            *(short8*)&sB[row][c8*8] =
                *(const short8*)(BT + (size_t)(n0 + row) * CC + kt + c8*8);
        }
        __syncthreads();
        #pragma unroll
        for (int kk = 0; kk < 2; ++kk) {
            hv8 af[4], bf[4];
            #pragma unroll
            for (int mi = 0; mi < 4; ++mi)
                af[mi] = *(const hv8*)&sA[mw + mi*16 + l16][kk*32 + quad*8];
            #pragma unroll
            for (int nj = 0; nj < 4; ++nj)
                bf[nj] = *(const hv8*)&sB[nw + nj*16 + l16][kk*32 + quad*8];
            #pragma unroll
            for (int mi = 0; mi < 4; ++mi)
                #pragma unroll
                for (int nj = 0; nj < 4; ++nj)
                    acc[mi][nj] = __builtin_amdgcn_mfma_f32_16x16x32_f16(
                        af[mi], bf[nj], acc[mi][nj], 0, 0, 0);
        }
        __syncthreads();
    }

    #pragma unroll
    for (int mi = 0; mi < 4; ++mi)
        #pragma unroll
        for (int nj = 0; nj < 4; ++nj)
            #pragma unroll
            for (int r = 0; r < 4; ++r) {
                int gm = m0 + mw + mi*16 + quad*4 + r;
                int gn = n0 + nw + nj*16 + l16;
                int bI = gm >> 10, tI = gm & 1023;
                int hI = gn >> 6,  dI = gn & 63;
                Chead[(((size_t)bI * NH + hI) * TT + tI) * HD + dI] =
                    (_Float16)(acc[mi][nj][r] * scale);
            }
}

// ---------------------------------------------------------------------------
// fp16 single-pass output GEMM: out(fp32) = A @ BT^T + bias
// ---------------------------------------------------------------------------
__global__ __launch_bounds__(256) void gemm_out_f16(
    const _Float16* __restrict__ A, const _Float16* __restrict__ BT,
    const float* __restrict__ bias, float* __restrict__ out)
{
    __shared__ _Float16 sA[128][72];
    __shared__ _Float16 sB[128][72];

    const int tid  = threadIdx.x;
    const int wave = tid >> 6, lane = tid & 63;
    const int quad = lane >> 4, l16 = lane & 15;
    const int m0 = blockIdx.y * 128, n0 = blockIdx.x * 128;
    const int mw = (wave & 1) * 64, nw = (wave >> 1) * 64;

    f32x4 acc[4][4];
    #pragma unroll
    for (int i = 0; i < 4; ++i)
        #pragma unroll
        for (int j = 0; j < 4; ++j) acc[i][j] = (f32x4){0.f,0.f,0.f,0.f};

    for (int kt = 0; kt < CC; kt += 64) {
        #pragma unroll
        for (int ii = 0; ii < 4; ++ii) {
            int u = tid + ii * 256;
            int row = u >> 3, c8 = u & 7;
            *(short8*)&sA[row][c8*8] =
                *(const short8*)(A  + (size_t)(m0 + row) * CC + kt + c8*8);
            *(short8*)&sB[row][c8*8] =
                *(const short8*)(BT + (size_t)(n0 + row) * CC + kt + c8*8);
        }
        __syncthreads();
        #pragma unroll
        for (int kk = 0; kk < 2; ++kk) {
            hv8 af[4], bf[4];
            #pragma unroll
            for (int mi = 0; mi < 4; ++mi)
                af[mi] = *(const hv8*)&sA[mw + mi*16 + l16][kk*32 + quad*8];
            #pragma unroll
            for (int nj = 0; nj < 4; ++nj)
                bf[nj] = *(const hv8*)&sB[nw + nj*16 + l16][kk*32 + quad*8];
            #pragma unroll
            for (int mi = 0; mi < 4; ++mi)
                #pragma unroll
                for (int nj = 0; nj < 4; ++nj)
                    acc[mi][nj] = __builtin_amdgcn_mfma_f32_16x16x32_f16(
                        af[mi], bf[nj], acc[mi][nj], 0, 0, 0);
        }
        __syncthreads();
    }

    #pragma unroll
    for (int mi = 0; mi < 4; ++mi)
        #pragma unroll
        for (int nj = 0; nj < 4; ++nj)
            #pragma unroll
            for (int r = 0; r < 4; ++r) {
                int gm = m0 + mw + mi*16 + quad*4 + r;
                int gn = n0 + nw + nj*16 + l16;
                out[(size_t)gm * CC + gn] = acc[mi][nj][r] + bias[gn];
            }
}

// ---------------------------------------------------------------------------
// fp16 MFMA flash attention, rel-pos bias via MFMA.
// Block = (b, h, 64-q tile), 4 waves.  K pre-scaled by 1/8.  V given
// transposed ([b,h,d,t]).  sP: per-wave 16x72 regions offset by +8 shorts
// (de-aliases quads; b128-aligned).  LDS 32.1 KB -> 4 blocks/CU.
// ---------------------------------------------------------------------------
#define PW (16*72 + 8)   // per-wave sP region stride (shorts)

__global__ __launch_bounds__(256) void attn_mfma(
    const _Float16* __restrict__ Q, const _Float16* __restrict__ K,
    const _Float16* __restrict__ Vt, const float* __restrict__ relh,
    const float* __restrict__ relw, _Float16* __restrict__ O)
{
    __shared__ _Float16 sK [64][72];   // loop: K tile | prologue: relh window
    __shared__ _Float16 sVt[64][72];   // loop: Vt tile | prologue: relw rows
    __shared__ _Float16 sP [4*PW];     // loop: per-wave P | prologue: Q (stride 72) + G
    __shared__ _Float16 sH [64][34];   // rh table [qi][hk]

    const int tid  = threadIdx.x;
    const int wave = tid >> 6, lane = tid & 63;
    const int quad = lane >> 4, l16 = lane & 15;

    const int bid = blockIdx.x;
    const int qt  = bid & 15;
    const int bh  = bid >> 4;
    const int h   = bh % NH;
    const int b   = bh / NH;
    const size_t hbase = ((size_t)b * NH + h) * TT * HD;

    // ---- prologue staging: Q (stride-72 overlay on sP), relh window, relw
    #pragma unroll
    for (int ii = 0; ii < 2; ++ii) {
        int u = tid + ii * 256;
        int row = u >> 3, c8 = u & 7;
        *(short8*)&sP[row*72 + c8*8] =
            *(const short8*)(Q + hbase + (size_t)(qt*64 + row) * HD + c8*8);
    }
    #pragma unroll
    for (int ii = 0; ii < 2; ++ii) {
        int u = tid + ii * 256;
        if (u < 264) {                 // 33 rows x 8 chunks of relh window
            int row = u >> 3, c8 = u & 7;
            const float* src = relh + (size_t)(2*qt + row) * HD + c8*8;
            float4 v0 = *(const float4*)(src);
            float4 v1 = *(const float4*)(src + 4);
            hv8 s = { (_Float16)v0.x, (_Float16)v0.y, (_Float16)v0.z, (_Float16)v0.w,
                      (_Float16)v1.x, (_Float16)v1.y, (_Float16)v1.z, (_Float16)v1.w };
            *(hv8*)&sK[row][c8*8] = s;
        }
    }
    #pragma unroll
    for (int ii = 0; ii < 2; ++ii) {
        int u = tid + ii * 256;
        int row = u >> 3, c8 = u & 7;
        int sr = row < 63 ? row : 62;
        const float* src = relw + (size_t)sr * HD + c8*8;
        float4 v0 = *(const float4*)(src);
        float4 v1 = *(const float4*)(src + 4);
        hv8 s = { (_Float16)v0.x, (_Float16)v0.y, (_Float16)v0.z, (_Float16)v0.w,
                  (_Float16)v1.x, (_Float16)v1.y, (_Float16)v1.z, (_Float16)v1.w };
        *(hv8*)&sVt[row][c8*8] = s;
    }
    __syncthreads();

    // ---- persistent Q A-fragments
    const int qrow = wave*16 + l16;
    hv8 aQ0 = *(const hv8*)&sP[qrow*72 + quad*8];
    hv8 aQ1 = *(const hv8*)&sP[qrow*72 + 32 + quad*8];
    __syncthreads();   // all aQ loaded before G-writes clobber the overlay

    // ---- RH via MFMA: sH[qi][hk] = q . relh[hq-hk+31]  (hq wave-uniform)
    const int hqLoc = wave >> 1;
    #pragma unroll
    for (int t = 0; t < 2; ++t) {
        int wr = hqLoc + 31 - (t*16 + l16);          // in [0,32]
        hv8 b0 = *(const hv8*)&sK[wr][quad*8];
        hv8 b1 = *(const hv8*)&sK[wr][32 + quad*8];
        f32x4 c = {0.f,0.f,0.f,0.f};
        c = __builtin_amdgcn_mfma_f32_16x16x32_f16(aQ0, b0, c, 0, 0, 0);
        c = __builtin_amdgcn_mfma_f32_16x16x32_f16(aQ1, b1, c, 0, 0, 0);
        #pragma unroll
        for (int r = 0; r < 4; ++r)
            sH[wave*16 + quad*4 + r][t*16 + l16] = (_Float16)c[r];
    }
    // ---- G = Q @ relw^T into own-wave sP region (col 63 garbage, unused)
    #pragma unroll
    for (int t = 0; t < 4; ++t) {
        hv8 b0 = *(const hv8*)&sVt[t*16 + l16][quad*8];
        hv8 b1 = *(const hv8*)&sVt[t*16 + l16][32 + quad*8];
        f32x4 c = {0.f,0.f,0.f,0.f};
        c = __builtin_amdgcn_mfma_f32_16x16x32_f16(aQ0, b0, c, 0, 0, 0);
        c = __builtin_amdgcn_mfma_f32_16x16x32_f16(aQ1, b1, c, 0, 0, 0);
        #pragma unroll
        for (int r = 0; r < 4; ++r)
            sP[wave*PW + (quad*4 + r)*72 + t*16 + l16] = (_Float16)c[r];
    }
    // ---- gather RW bias (own wave region; waitcnt orders same-wave LDS)
    float rwReg[2][4];
    #pragma unroll
    for (int j = 0; j < 2; ++j)
        #pragma unroll
        for (int r = 0; r < 4; ++r) {
            int idx = (wave&1)*16 + quad*4 + r - j*16 - l16 + 31;  // 0..62
            rwReg[j][r] = (float)sP[wave*PW + (quad*4 + r)*72 + idx];
        }
    __syncthreads();

    f32x4 o[4] = {{0.f,0.f,0.f,0.f},{0.f,0.f,0.f,0.f},
                  {0.f,0.f,0.f,0.f},{0.f,0.f,0.f,0.f}};
    float l[4] = {0.f,0.f,0.f,0.f};

    for (int kt = 0; kt < 16; ++kt) {
        // ---- stage K [kj][d] and Vt [d][kj] tiles (all b128)
        #pragma unroll
        for (int ii = 0; ii < 2; ++ii) {
            int u = tid + ii * 256;
            int row = u >> 3, c8 = u & 7;
            *(short8*)&sK[row][c8*8] =
                *(const short8*)(K + hbase + (size_t)(kt*64 + row) * HD + c8*8);
            *(short8*)&sVt[row][c8*8] =
                *(const short8*)(Vt + hbase + (size_t)row * TT + kt*64 + c8*8);
        }
        __syncthreads();

        // ---- per-row RH bias for this k-tile (broadcast reads)
        float rh[2][4];
        #pragma unroll
        for (int t2 = 0; t2 < 2; ++t2)
            #pragma unroll
            for (int r = 0; r < 4; ++r)
                rh[t2][r] = (float)sH[wave*16 + quad*4 + r][kt*2 + t2];

        // ---- scores + exp + pack P
        float rs[4] = {0.f,0.f,0.f,0.f};
        #pragma unroll
        for (int bb = 0; bb < 4; ++bb) {
            hv8 bK0 = *(const hv8*)&sK[bb*16 + l16][quad*8];
            hv8 bK1 = *(const hv8*)&sK[bb*16 + l16][32 + quad*8];
            f32x4 c = {0.f,0.f,0.f,0.f};
            c = __builtin_amdgcn_mfma_f32_16x16x32_f16(aQ0, bK0, c, 0, 0, 0);
            c = __builtin_amdgcn_mfma_f32_16x16x32_f16(aQ1, bK1, c, 0, 0, 0);
            #pragma unroll
            for (int r = 0; r < 4; ++r) {
                float p = __expf(c[r] + rh[bb>>1][r] + rwReg[bb&1][r]);
                rs[r] += p;
                sP[wave*PW + (quad*4 + r)*72 + bb*16 + l16] = (_Float16)p;
            }
        }
        #pragma unroll
        for (int r = 0; r < 4; ++r) {
            float t = rs[r];
            t += __shfl_xor(t, 1);
            t += __shfl_xor(t, 2);
            t += __shfl_xor(t, 4);
            t += __shfl_xor(t, 8);
            l[r] += t;
        }

        // ---- O += P @ V  (B-frags straight from Vt rows)
        hv8 aP0 = *(const hv8*)&sP[wave*PW + l16*72 + quad*8];
        hv8 aP1 = *(const hv8*)&sP[wave*PW + l16*72 + 32 + quad*8];
        #pragma unroll
        for (int n = 0; n < 4; ++n) {
            hv8 bV0 = *(const hv8*)&sVt[n*16 + l16][quad*8];
            hv8 bV1 = *(const hv8*)&sVt[n*16 + l16][32 + quad*8];
            o[n] = __builtin_amdgcn_mfma_f32_16x16x32_f16(aP0, bV0, o[n], 0, 0, 0);
            o[n] = __builtin_amdgcn_mfma_f32_16x16x32_f16(aP1, bV1, o[n], 0, 0, 0);
        }
        __syncthreads();
    }

    // ---- finalize: /l, fp16 out into [b, t, C]
    float inv[4];
    #pragma unroll
    for (int r = 0; r < 4; ++r) inv[r] = 1.f / l[r];
    #pragma unroll
    for (int n = 0; n < 4; ++n)
        #pragma unroll
        for (int r = 0; r < 4; ++r) {
            int t = qt*64 + wave*16 + quad*4 + r;
            size_t addr = ((size_t)b * TT + t) * CC + h*HD + n*16 + l16;
            O[addr] = (_Float16)(o[n][r] * inv[r]);
        }
}

// ---------------------------------------------------------------------------
extern "C" void kernel_launch(void* const* d_in, const int* in_sizes, int n_in,
                              void* d_out, int out_size, void* d_ws, size_t ws_size,
                              hipStream_t stream) {
    const float* x   = (const float*)d_in[0];
    const float* ctx = (const float*)d_in[1];
    const float* Wq  = (const float*)d_in[2];
    const float* Wk  = (const float*)d_in[3];
    const float* Wv  = (const float*)d_in[4];
    const float* Wo  = (const float*)d_in[5];
    const float* bo  = (const float*)d_in[6];
    const float* rh  = (const float*)d_in[7];
    const float* rw  = (const float*)d_in[8];
    float* out = (float*)d_out;

    const size_t MN = (size_t)BB * TT * CC;   // 6291456
    const size_t WN = (size_t)CC * CC;        // 589824
    _Float16* p = (_Float16*)d_ws;
    _Float16* xh   = p; p += MN;
    _Float16* ch   = p; p += MN;
    _Float16* WqT  = p; p += WN;
    _Float16* WkT  = p; p += WN;
    _Float16* WvT  = p; p += WN;
    _Float16* WoT  = p; p += WN;
    _Float16* Qh   = p; p += MN;
    _Float16* Kh   = p; p += MN;
    _Float16* Vh   = p; p += MN;
    _Float16* VtB  = p; p += MN;
    _Float16* Oh   = p; p += MN;

    dim3 blk(256);

    convert_f16<<<dim3(MN/2048), blk, 0, stream>>>(x,   xh, (int)MN);
    convert_f16<<<dim3(MN/2048), blk, 0, stream>>>(ctx, ch, (int)MN);

    dim3 gt(12, 12);
    transpose_w<<<gt, blk, 0, stream>>>(Wq, WqT);
    transpose_w<<<gt, blk, 0, stream>>>(Wk, WkT);
    transpose_w<<<gt, blk, 0, stream>>>(Wv, WvT);
    transpose_w<<<gt, blk, 0, stream>>>(Wo, WoT);

    dim3 gg(CC/128, (BB*TT)/128);   // (6, 64)
    gemm_qkv<<<gg, blk, 0, stream>>>(xh, WqT, Qh, 1.0f);
    gemm_qkv<<<gg, blk, 0, stream>>>(ch, WkT, Kh, 0.125f);  // fold score scale into K
    gemm_qkv<<<gg, blk, 0, stream>>>(ch, WvT, Vh, 1.0f);

    vtrans<<<dim3(16, BB*NH), blk, 0, stream>>>(Vh, VtB);

    attn_mfma<<<dim3(BB*NH*(TT/64)), blk, 0, stream>>>(Qh, Kh, VtB, rh, rw, Oh);

    gemm_out_f16<<<gg, blk, 0, stream>>>(Oh, WoT, bo, out);
}

// Round 6
// 290.539 us; speedup vs baseline: 4.7234x; 1.0464x over previous
//
#include <hip/hip_runtime.h>
#include <math.h>

#define BB 8
#define TT 1024
#define CC 768
#define NH 12
#define HD 64

typedef __attribute__((ext_vector_type(8))) _Float16 hv8;   // 8 fp16 (4 VGPRs)
typedef __attribute__((ext_vector_type(8))) short  short8;  // raw 16B
typedef __attribute__((ext_vector_type(4))) float  f32x4;

// ---------------------------------------------------------------------------
// All 4 weight transposes in one launch: WT[n][k] = W[k][n] * scale (fp16).
// z selects the weight; 0.125 score scale folded into Wk (pow2 -> exact).
// ---------------------------------------------------------------------------
__global__ __launch_bounds__(256) void transpose_w4(
    const float* __restrict__ Wq, const float* __restrict__ Wk,
    const float* __restrict__ Wv, const float* __restrict__ Wo,
    _Float16* __restrict__ WqT, _Float16* __restrict__ WkT,
    _Float16* __restrict__ WvT, _Float16* __restrict__ WoT)
{
    const int z = blockIdx.z;
    const float* W = (z == 0) ? Wq : (z == 1) ? Wk : (z == 2) ? Wv : Wo;
    _Float16*   WT = (z == 0) ? WqT : (z == 1) ? WkT : (z == 2) ? WvT : WoT;
    const float scale = (z == 1) ? 0.125f : 1.0f;

    __shared__ float tile[64][65];
    const int tx = threadIdx.x & 15, ty = threadIdx.x >> 4;
    const int n0 = blockIdx.x * 64, k0 = blockIdx.y * 64;

    #pragma unroll
    for (int ii = 0; ii < 4; ++ii) {
        int k = ty + ii * 16;
        float4 v = *(const float4*)(W + (size_t)(k0 + k) * CC + n0 + tx * 4);
        tile[k][tx*4+0] = v.x; tile[k][tx*4+1] = v.y;
        tile[k][tx*4+2] = v.z; tile[k][tx*4+3] = v.w;
    }
    __syncthreads();
    #pragma unroll
    for (int ii = 0; ii < 4; ++ii) {
        int n = ty + ii * 16;
        _Float16* dst = WT + (size_t)(n0 + n) * CC + k0 + tx * 4;
        dst[0] = (_Float16)(tile[tx*4+0][n] * scale);
        dst[1] = (_Float16)(tile[tx*4+1][n] * scale);
        dst[2] = (_Float16)(tile[tx*4+2][n] * scale);
        dst[3] = (_Float16)(tile[tx*4+3][n] * scale);
    }
}

// ---------------------------------------------------------------------------
// Fused QKV GEMM, one launch (grid.z = 0/1/2 -> Q/K/V).
// C = A(fp32, converted in staging) @ BT^T, 128x128 tile, BK=64, 4 waves.
// z<2: fp16 out head-major [b,h,t,d].  z==2 (V): LDS bounce-transpose
// epilogue, fp16 out [b,h,d,t] (what attention wants for its B-fragments).
// ---------------------------------------------------------------------------
__global__ __launch_bounds__(256) void gemm_qkv3(
    const float* __restrict__ x, const float* __restrict__ ctx,
    const _Float16* __restrict__ WqT, const _Float16* __restrict__ WkT,
    const _Float16* __restrict__ WvT,
    _Float16* __restrict__ Qh, _Float16* __restrict__ Kh,
    _Float16* __restrict__ Vt)
{
    const int z = blockIdx.z;
    const float*    A  = (z == 0) ? x : ctx;
    const _Float16* BT = (z == 0) ? WqT : (z == 1) ? WkT : WvT;

    __shared__ _Float16 smem[2 * 128 * 72];   // sA | sB ; reused as sT for V
    _Float16* sA = smem;
    _Float16* sB = smem + 128 * 72;

    const int tid  = threadIdx.x;
    const int wave = tid >> 6, lane = tid & 63;
    const int quad = lane >> 4, l16 = lane & 15;
    const int m0 = blockIdx.y * 128, n0 = blockIdx.x * 128;
    const int mw = (wave & 1) * 64, nw = (wave >> 1) * 64;

    f32x4 acc[4][4];
    #pragma unroll
    for (int i = 0; i < 4; ++i)
        #pragma unroll
        for (int j = 0; j < 4; ++j) acc[i][j] = (f32x4){0.f,0.f,0.f,0.f};

    for (int kt = 0; kt < CC; kt += 64) {
        #pragma unroll
        for (int ii = 0; ii < 4; ++ii) {
            int u = tid + ii * 256;
            int row = u >> 3, c8 = u & 7;
            const float* ap = A + (size_t)(m0 + row) * CC + kt + c8*8;
            float4 a0 = *(const float4*)(ap);
            float4 a1 = *(const float4*)(ap + 4);
            hv8 av = { (_Float16)a0.x, (_Float16)a0.y, (_Float16)a0.z, (_Float16)a0.w,
                       (_Float16)a1.x, (_Float16)a1.y, (_Float16)a1.z, (_Float16)a1.w };
            *(hv8*)&sA[row*72 + c8*8] = av;
            *(short8*)&sB[row*72 + c8*8] =
                *(const short8*)(BT + (size_t)(n0 + row) * CC + kt + c8*8);
        }
        __syncthreads();
        #pragma unroll
        for (int kk = 0; kk < 2; ++kk) {
            hv8 af[4], bf[4];
            #pragma unroll
            for (int mi = 0; mi < 4; ++mi)
                af[mi] = *(const hv8*)&sA[(mw + mi*16 + l16)*72 + kk*32 + quad*8];
            #pragma unroll
            for (int nj = 0; nj < 4; ++nj)
                bf[nj] = *(const hv8*)&sB[(nw + nj*16 + l16)*72 + kk*32 + quad*8];
            #pragma unroll
            for (int mi = 0; mi < 4; ++mi)
                #pragma unroll
                for (int nj = 0; nj < 4; ++nj)
                    acc[mi][nj] = __builtin_amdgcn_mfma_f32_16x16x32_f16(
                        af[mi], bf[nj], acc[mi][nj], 0, 0, 0);
        }
        __syncthreads();
    }

    if (z < 2) {
        _Float16* Chead = (z == 0) ? Qh : Kh;
        #pragma unroll
        for (int mi = 0; mi < 4; ++mi)
            #pragma unroll
            for (int nj = 0; nj < 4; ++nj)
                #pragma unroll
                for (int r = 0; r < 4; ++r) {
                    int gm = m0 + mw + mi*16 + quad*4 + r;
                    int gn = n0 + nw + nj*16 + l16;
                    int bI = gm >> 10, tI = gm & 1023;
                    int hI = gn >> 6,  dI = gn & 63;
                    Chead[(((size_t)bI * NH + hI) * TT + tI) * HD + dI] =
                        (_Float16)acc[mi][nj][r];
                }
    } else {
        // V: bounce through LDS (stride 137 half-dword rotation not needed:
        // 2-way aliasing is free), then scatter-store [b,h,d,t].
        _Float16* sT = smem;   // [128][136]
        #pragma unroll
        for (int mi = 0; mi < 4; ++mi)
            #pragma unroll
            for (int nj = 0; nj < 4; ++nj)
                #pragma unroll
                for (int r = 0; r < 4; ++r)
                    sT[(mw + mi*16 + quad*4 + r)*136 + nw + nj*16 + l16] =
                        (_Float16)acc[mi][nj][r];
        __syncthreads();
        #pragma unroll
        for (int ii = 0; ii < 8; ++ii) {
            int u = tid + ii * 256;
            int dloc = u & 127, tch = u >> 7;   // lanes sweep d -> 2-way LDS
            hv8 o;
            #pragma unroll
            for (int j = 0; j < 8; ++j) o[j] = sT[(tch*8 + j)*136 + dloc];
            int gn = n0 + dloc;
            int hI = gn >> 6, dI = gn & 63;
            int gm = m0 + tch * 8;
            int bI = gm >> 10, tI = gm & 1023;
            *(hv8*)(Vt + (((size_t)bI * NH + hI) * HD + dI) * TT + tI) = o;
        }
    }
}

// ---------------------------------------------------------------------------
// fp16 single-pass output GEMM: out(fp32) = A @ BT^T + bias
// ---------------------------------------------------------------------------
__global__ __launch_bounds__(256) void gemm_out_f16(
    const _Float16* __restrict__ A, const _Float16* __restrict__ BT,
    const float* __restrict__ bias, float* __restrict__ out)
{
    __shared__ _Float16 sA[128][72];
    __shared__ _Float16 sB[128][72];

    const int tid  = threadIdx.x;
    const int wave = tid >> 6, lane = tid & 63;
    const int quad = lane >> 4, l16 = lane & 15;
    const int m0 = blockIdx.y * 128, n0 = blockIdx.x * 128;
    const int mw = (wave & 1) * 64, nw = (wave >> 1) * 64;

    f32x4 acc[4][4];
    #pragma unroll
    for (int i = 0; i < 4; ++i)
        #pragma unroll
        for (int j = 0; j < 4; ++j) acc[i][j] = (f32x4){0.f,0.f,0.f,0.f};

    for (int kt = 0; kt < CC; kt += 64) {
        #pragma unroll
        for (int ii = 0; ii < 4; ++ii) {
            int u = tid + ii * 256;
            int row = u >> 3, c8 = u & 7;
            *(short8*)&sA[row][c8*8] =
                *(const short8*)(A  + (size_t)(m0 + row) * CC + kt + c8*8);
            *(short8*)&sB[row][c8*8] =
                *(const short8*)(BT + (size_t)(n0 + row) * CC + kt + c8*8);
        }
        __syncthreads();
        #pragma unroll
        for (int kk = 0; kk < 2; ++kk) {
            hv8 af[4], bf[4];
            #pragma unroll
            for (int mi = 0; mi < 4; ++mi)
                af[mi] = *(const hv8*)&sA[mw + mi*16 + l16][kk*32 + quad*8];
            #pragma unroll
            for (int nj = 0; nj < 4; ++nj)
                bf[nj] = *(const hv8*)&sB[nw + nj*16 + l16][kk*32 + quad*8];
            #pragma unroll
            for (int mi = 0; mi < 4; ++mi)
                #pragma unroll
                for (int nj = 0; nj < 4; ++nj)
                    acc[mi][nj] = __builtin_amdgcn_mfma_f32_16x16x32_f16(
                        af[mi], bf[nj], acc[mi][nj], 0, 0, 0);
        }
        __syncthreads();
    }

    #pragma unroll
    for (int mi = 0; mi < 4; ++mi)
        #pragma unroll
        for (int nj = 0; nj < 4; ++nj)
            #pragma unroll
            for (int r = 0; r < 4; ++r) {
                int gm = m0 + mw + mi*16 + quad*4 + r;
                int gn = n0 + nw + nj*16 + l16;
                out[(size_t)gm * CC + gn] = acc[mi][nj][r] + bias[gn];
            }
}

// ---------------------------------------------------------------------------
// fp16 MFMA flash attention, rel-pos bias via MFMA (unchanged from round 5).
// Block = (b, h, 64-q tile), 4 waves.  K pre-scaled by 1/8.  V given
// transposed ([b,h,d,t]).  LDS 32.1 KB -> 4 blocks/CU.
// ---------------------------------------------------------------------------
#define PW (16*72 + 8)   // per-wave sP region stride (shorts)

__global__ __launch_bounds__(256) void attn_mfma(
    const _Float16* __restrict__ Q, const _Float16* __restrict__ K,
    const _Float16* __restrict__ Vt, const float* __restrict__ relh,
    const float* __restrict__ relw, _Float16* __restrict__ O)
{
    __shared__ _Float16 sK [64][72];   // loop: K tile | prologue: relh window
    __shared__ _Float16 sVt[64][72];   // loop: Vt tile | prologue: relw rows
    __shared__ _Float16 sP [4*PW];     // loop: per-wave P | prologue: Q + G
    __shared__ _Float16 sH [64][34];   // rh table [qi][hk]

    const int tid  = threadIdx.x;
    const int wave = tid >> 6, lane = tid & 63;
    const int quad = lane >> 4, l16 = lane & 15;

    const int bid = blockIdx.x;
    const int qt  = bid & 15;
    const int bh  = bid >> 4;
    const int h   = bh % NH;
    const int b   = bh / NH;
    const size_t hbase = ((size_t)b * NH + h) * TT * HD;

    // ---- prologue staging: Q (stride-72 overlay on sP), relh window, relw
    #pragma unroll
    for (int ii = 0; ii < 2; ++ii) {
        int u = tid + ii * 256;
        int row = u >> 3, c8 = u & 7;
        *(short8*)&sP[row*72 + c8*8] =
            *(const short8*)(Q + hbase + (size_t)(qt*64 + row) * HD + c8*8);
    }
    #pragma unroll
    for (int ii = 0; ii < 2; ++ii) {
        int u = tid + ii * 256;
        if (u < 264) {                 // 33 rows x 8 chunks of relh window
            int row = u >> 3, c8 = u & 7;
            const float* src = relh + (size_t)(2*qt + row) * HD + c8*8;
            float4 v0 = *(const float4*)(src);
            float4 v1 = *(const float4*)(src + 4);
            hv8 s = { (_Float16)v0.x, (_Float16)v0.y, (_Float16)v0.z, (_Float16)v0.w,
                      (_Float16)v1.x, (_Float16)v1.y, (_Float16)v1.z, (_Float16)v1.w };
            *(hv8*)&sK[row][c8*8] = s;
        }
    }
    #pragma unroll
    for (int ii = 0; ii < 2; ++ii) {
        int u = tid + ii * 256;
        int row = u >> 3, c8 = u & 7;
        int sr = row < 63 ? row : 62;
        const float* src = relw + (size_t)sr * HD + c8*8;
        float4 v0 = *(const float4*)(src);
        float4 v1 = *(const float4*)(src + 4);
        hv8 s = { (_Float16)v0.x, (_Float16)v0.y, (_Float16)v0.z, (_Float16)v0.w,
                  (_Float16)v1.x, (_Float16)v1.y, (_Float16)v1.z, (_Float16)v1.w };
        *(hv8*)&sVt[row][c8*8] = s;
    }
    __syncthreads();

    // ---- persistent Q A-fragments
    const int qrow = wave*16 + l16;
    hv8 aQ0 = *(const hv8*)&sP[qrow*72 + quad*8];
    hv8 aQ1 = *(const hv8*)&sP[qrow*72 + 32 + quad*8];
    __syncthreads();   // all aQ loaded before G-writes clobber the overlay

    // ---- RH via MFMA: sH[qi][hk] = q . relh[hq-hk+31]  (hq wave-uniform)
    const int hqLoc = wave >> 1;
    #pragma unroll
    for (int t = 0; t < 2; ++t) {
        int wr = hqLoc + 31 - (t*16 + l16);          // in [0,32]
        hv8 b0 = *(const hv8*)&sK[wr][quad*8];
        hv8 b1 = *(const hv8*)&sK[wr][32 + quad*8];
        f32x4 c = {0.f,0.f,0.f,0.f};
        c = __builtin_amdgcn_mfma_f32_16x16x32_f16(aQ0, b0, c, 0, 0, 0);
        c = __builtin_amdgcn_mfma_f32_16x16x32_f16(aQ1, b1, c, 0, 0, 0);
        #pragma unroll
        for (int r = 0; r < 4; ++r)
            sH[wave*16 + quad*4 + r][t*16 + l16] = (_Float16)c[r];
    }
    // ---- G = Q @ relw^T into own-wave sP region (col 63 garbage, unused)
    #pragma unroll
    for (int t = 0; t < 4; ++t) {
        hv8 b0 = *(const hv8*)&sVt[t*16 + l16][quad*8];
        hv8 b1 = *(const hv8*)&sVt[t*16 + l16][32 + quad*8];
        f32x4 c = {0.f,0.f,0.f,0.f};
        c = __builtin_amdgcn_mfma_f32_16x16x32_f16(aQ0, b0, c, 0, 0, 0);
        c = __builtin_amdgcn_mfma_f32_16x16x32_f16(aQ1, b1, c, 0, 0, 0);
        #pragma unroll
        for (int r = 0; r < 4; ++r)
            sP[wave*PW + (quad*4 + r)*72 + t*16 + l16] = (_Float16)c[r];
    }
    // ---- gather RW bias (own wave region; waitcnt orders same-wave LDS)
    float rwReg[2][4];
    #pragma unroll
    for (int j = 0; j < 2; ++j)
        #pragma unroll
        for (int r = 0; r < 4; ++r) {
            int idx = (wave&1)*16 + quad*4 + r - j*16 - l16 + 31;  // 0..62
            rwReg[j][r] = (float)sP[wave*PW + (quad*4 + r)*72 + idx];
        }
    __syncthreads();

    f32x4 o[4] = {{0.f,0.f,0.f,0.f},{0.f,0.f,0.f,0.f},
                  {0.f,0.f,0.f,0.f},{0.f,0.f,0.f,0.f}};
    float l[4] = {0.f,0.f,0.f,0.f};

    for (int kt = 0; kt < 16; ++kt) {
        // ---- stage K [kj][d] and Vt [d][kj] tiles (all b128)
        #pragma unroll
        for (int ii = 0; ii < 2; ++ii) {
            int u = tid + ii * 256;
            int row = u >> 3, c8 = u & 7;
            *(short8*)&sK[row][c8*8] =
                *(const short8*)(K + hbase + (size_t)(kt*64 + row) * HD + c8*8);
            *(short8*)&sVt[row][c8*8] =
                *(const short8*)(Vt + hbase + (size_t)row * TT + kt*64 + c8*8);
        }
        __syncthreads();

        // ---- per-row RH bias for this k-tile (broadcast reads)
        float rh[2][4];
        #pragma unroll
        for (int t2 = 0; t2 < 2; ++t2)
            #pragma unroll
            for (int r = 0; r < 4; ++r)
                rh[t2][r] = (float)sH[wave*16 + quad*4 + r][kt*2 + t2];

        // ---- scores + exp + pack P
        float rs[4] = {0.f,0.f,0.f,0.f};
        #pragma unroll
        for (int bb = 0; bb < 4; ++bb) {
            hv8 bK0 = *(const hv8*)&sK[bb*16 + l16][quad*8];
            hv8 bK1 = *(const hv8*)&sK[bb*16 + l16][32 + quad*8];
            f32x4 c = {0.f,0.f,0.f,0.f};
            c = __builtin_amdgcn_mfma_f32_16x16x32_f16(aQ0, bK0, c, 0, 0, 0);
            c = __builtin_amdgcn_mfma_f32_16x16x32_f16(aQ1, bK1, c, 0, 0, 0);
            #pragma unroll
            for (int r = 0; r < 4; ++r) {
                float p = __expf(c[r] + rh[bb>>1][r] + rwReg[bb&1][r]);
                rs[r] += p;
                sP[wave*PW + (quad*4 + r)*72 + bb*16 + l16] = (_Float16)p;
            }
        }
        #pragma unroll
        for (int r = 0; r < 4; ++r) {
            float t = rs[r];
            t += __shfl_xor(t, 1);
            t += __shfl_xor(t, 2);
            t += __shfl_xor(t, 4);
            t += __shfl_xor(t, 8);
            l[r] += t;
        }

        // ---- O += P @ V  (B-frags straight from Vt rows)
        hv8 aP0 = *(const hv8*)&sP[wave*PW + l16*72 + quad*8];
        hv8 aP1 = *(const hv8*)&sP[wave*PW + l16*72 + 32 + quad*8];
        #pragma unroll
        for (int n = 0; n < 4; ++n) {
            hv8 bV0 = *(const hv8*)&sVt[n*16 + l16][quad*8];
            hv8 bV1 = *(const hv8*)&sVt[n*16 + l16][32 + quad*8];
            o[n] = __builtin_amdgcn_mfma_f32_16x16x32_f16(aP0, bV0, o[n], 0, 0, 0);
            o[n] = __builtin_amdgcn_mfma_f32_16x16x32_f16(aP1, bV1, o[n], 0, 0, 0);
        }
        __syncthreads();
    }

    // ---- finalize: /l, fp16 out into [b, t, C]
    float inv[4];
    #pragma unroll
    for (int r = 0; r < 4; ++r) inv[r] = 1.f / l[r];
    #pragma unroll
    for (int n = 0; n < 4; ++n)
        #pragma unroll
        for (int r = 0; r < 4; ++r) {
            int t = qt*64 + wave*16 + quad*4 + r;
            size_t addr = ((size_t)b * TT + t) * CC + h*HD + n*16 + l16;
            O[addr] = (_Float16)(o[n][r] * inv[r]);
        }
}

// ---------------------------------------------------------------------------
extern "C" void kernel_launch(void* const* d_in, const int* in_sizes, int n_in,
                              void* d_out, int out_size, void* d_ws, size_t ws_size,
                              hipStream_t stream) {
    const float* x   = (const float*)d_in[0];
    const float* ctx = (const float*)d_in[1];
    const float* Wq  = (const float*)d_in[2];
    const float* Wk  = (const float*)d_in[3];
    const float* Wv  = (const float*)d_in[4];
    const float* Wo  = (const float*)d_in[5];
    const float* bo  = (const float*)d_in[6];
    const float* rh  = (const float*)d_in[7];
    const float* rw  = (const float*)d_in[8];
    float* out = (float*)d_out;

    const size_t MN = (size_t)BB * TT * CC;   // 6291456
    const size_t WN = (size_t)CC * CC;        // 589824
    _Float16* p = (_Float16*)d_ws;
    _Float16* WqT = p; p += WN;
    _Float16* WkT = p; p += WN;
    _Float16* WvT = p; p += WN;
    _Float16* WoT = p; p += WN;
    _Float16* Qh  = p; p += MN;
    _Float16* Kh  = p; p += MN;
    _Float16* VtB = p; p += MN;
    _Float16* Oh  = p; p += MN;

    dim3 blk(256);

    transpose_w4<<<dim3(12, 12, 4), blk, 0, stream>>>(
        Wq, Wk, Wv, Wo, WqT, WkT, WvT, WoT);

    gemm_qkv3<<<dim3(CC/128, (BB*TT)/128, 3), blk, 0, stream>>>(
        x, ctx, WqT, WkT, WvT, Qh, Kh, VtB);

    attn_mfma<<<dim3(BB*NH*(TT/64)), blk, 0, stream>>>(
        Qh, Kh, VtB, rh, rw, Oh);

    gemm_out_f16<<<dim3(CC/128, (BB*TT)/128), blk, 0, stream>>>(
        Oh, WoT, bo, out);
}

// Round 7
// 256.712 us; speedup vs baseline: 5.3458x; 1.1318x over previous
//
#include <hip/hip_runtime.h>
#include <math.h>

#define BB 8
#define TT 1024
#define CC 768
#define NH 12
#define HD 64

typedef __attribute__((ext_vector_type(8))) _Float16 hv8;   // 8 fp16 (4 VGPRs)
typedef __attribute__((ext_vector_type(8))) short  short8;  // raw 16B
typedef __attribute__((ext_vector_type(4))) float  f32x4;

// ---------------------------------------------------------------------------
// fp32 -> fp16 convert; grid.z selects x / ctx.
// ---------------------------------------------------------------------------
__global__ __launch_bounds__(256) void convert_f16x2(
    const float* __restrict__ x, const float* __restrict__ ctx,
    _Float16* __restrict__ xh, _Float16* __restrict__ ch, int n)
{
    const float* in = blockIdx.z ? ctx : x;
    _Float16* out   = blockIdx.z ? ch  : xh;
    int i = (blockIdx.x * 256 + threadIdx.x) * 8;
    if (i < n) {
        float4 v0 = *(const float4*)(in + i);
        float4 v1 = *(const float4*)(in + i + 4);
        hv8 h = { (_Float16)v0.x, (_Float16)v0.y, (_Float16)v0.z, (_Float16)v0.w,
                  (_Float16)v1.x, (_Float16)v1.y, (_Float16)v1.z, (_Float16)v1.w };
        *(hv8*)(out + i) = h;
    }
}

// ---------------------------------------------------------------------------
// All 4 weight transposes in one launch: WT[n][k] = W[k][n] * scale (fp16).
// 0.125 score scale folded into Wk (pow2 -> exact).
// ---------------------------------------------------------------------------
__global__ __launch_bounds__(256) void transpose_w4(
    const float* __restrict__ Wq, const float* __restrict__ Wk,
    const float* __restrict__ Wv, const float* __restrict__ Wo,
    _Float16* __restrict__ WqT, _Float16* __restrict__ WkT,
    _Float16* __restrict__ WvT, _Float16* __restrict__ WoT)
{
    const int z = blockIdx.z;
    const float* W = (z == 0) ? Wq : (z == 1) ? Wk : (z == 2) ? Wv : Wo;
    _Float16*   WT = (z == 0) ? WqT : (z == 1) ? WkT : (z == 2) ? WvT : WoT;
    const float scale = (z == 1) ? 0.125f : 1.0f;

    __shared__ float tile[64][65];
    const int tx = threadIdx.x & 15, ty = threadIdx.x >> 4;
    const int n0 = blockIdx.x * 64, k0 = blockIdx.y * 64;

    #pragma unroll
    for (int ii = 0; ii < 4; ++ii) {
        int k = ty + ii * 16;
        float4 v = *(const float4*)(W + (size_t)(k0 + k) * CC + n0 + tx * 4);
        tile[k][tx*4+0] = v.x; tile[k][tx*4+1] = v.y;
        tile[k][tx*4+2] = v.z; tile[k][tx*4+3] = v.w;
    }
    __syncthreads();
    #pragma unroll
    for (int ii = 0; ii < 4; ++ii) {
        int n = ty + ii * 16;
        _Float16* dst = WT + (size_t)(n0 + n) * CC + k0 + tx * 4;
        dst[0] = (_Float16)(tile[tx*4+0][n] * scale);
        dst[1] = (_Float16)(tile[tx*4+1][n] * scale);
        dst[2] = (_Float16)(tile[tx*4+2][n] * scale);
        dst[3] = (_Float16)(tile[tx*4+3][n] * scale);
    }
}

// ---------------------------------------------------------------------------
// Fused QKV GEMM, one launch (grid.z = 0/1/2 -> Q/K/V), fp16 inputs.
// z<2: fp16 out head-major [b,h,t,d].  z==2 (V): stride-137 LDS bounce,
// t-contiguous 256B global stores into [b,h,d,t].
// ---------------------------------------------------------------------------
__global__ __launch_bounds__(256) void gemm_qkv3(
    const _Float16* __restrict__ xh, const _Float16* __restrict__ ch,
    const _Float16* __restrict__ WqT, const _Float16* __restrict__ WkT,
    const _Float16* __restrict__ WvT,
    _Float16* __restrict__ Qh, _Float16* __restrict__ Kh,
    _Float16* __restrict__ Vt)
{
    const int z = blockIdx.z;
    const _Float16* A  = (z == 0) ? xh : ch;
    const _Float16* BT = (z == 0) ? WqT : (z == 1) ? WkT : WvT;

    __shared__ _Float16 smem[2 * 128 * 72];   // sA | sB ; reused as sT for V
    _Float16* sA = smem;
    _Float16* sB = smem + 128 * 72;

    const int tid  = threadIdx.x;
    const int wave = tid >> 6, lane = tid & 63;
    const int quad = lane >> 4, l16 = lane & 15;
    const int m0 = blockIdx.y * 128, n0 = blockIdx.x * 128;
    const int mw = (wave & 1) * 64, nw = (wave >> 1) * 64;

    f32x4 acc[4][4];
    #pragma unroll
    for (int i = 0; i < 4; ++i)
        #pragma unroll
        for (int j = 0; j < 4; ++j) acc[i][j] = (f32x4){0.f,0.f,0.f,0.f};

    for (int kt = 0; kt < CC; kt += 64) {
        #pragma unroll
        for (int ii = 0; ii < 4; ++ii) {
            int u = tid + ii * 256;
            int row = u >> 3, c8 = u & 7;
            *(short8*)&sA[row*72 + c8*8] =
                *(const short8*)(A  + (size_t)(m0 + row) * CC + kt + c8*8);
            *(short8*)&sB[row*72 + c8*8] =
                *(const short8*)(BT + (size_t)(n0 + row) * CC + kt + c8*8);
        }
        __syncthreads();
        #pragma unroll
        for (int kk = 0; kk < 2; ++kk) {
            hv8 af[4], bf[4];
            #pragma unroll
            for (int mi = 0; mi < 4; ++mi)
                af[mi] = *(const hv8*)&sA[(mw + mi*16 + l16)*72 + kk*32 + quad*8];
            #pragma unroll
            for (int nj = 0; nj < 4; ++nj)
                bf[nj] = *(const hv8*)&sB[(nw + nj*16 + l16)*72 + kk*32 + quad*8];
            #pragma unroll
            for (int mi = 0; mi < 4; ++mi)
                #pragma unroll
                for (int nj = 0; nj < 4; ++nj)
                    acc[mi][nj] = __builtin_amdgcn_mfma_f32_16x16x32_f16(
                        af[mi], bf[nj], acc[mi][nj], 0, 0, 0);
        }
        __syncthreads();
    }

    if (z < 2) {
        _Float16* Chead = (z == 0) ? Qh : Kh;
        #pragma unroll
        for (int mi = 0; mi < 4; ++mi)
            #pragma unroll
            for (int nj = 0; nj < 4; ++nj)
                #pragma unroll
                for (int r = 0; r < 4; ++r) {
                    int gm = m0 + mw + mi*16 + quad*4 + r;
                    int gn = n0 + nw + nj*16 + l16;
                    int bI = gm >> 10, tI = gm & 1023;
                    int hI = gn >> 6,  dI = gn & 63;
                    Chead[(((size_t)bI * NH + hI) * TT + tI) * HD + dI] =
                        (_Float16)acc[mi][nj][r];
                }
    } else {
        // V: stride-137 bounce (<=2-way on writes), then t-contiguous stores.
        _Float16* sT = smem;   // [128][137] = 17536 halves <= 18432
        #pragma unroll
        for (int mi = 0; mi < 4; ++mi)
            #pragma unroll
            for (int nj = 0; nj < 4; ++nj)
                #pragma unroll
                for (int r = 0; r < 4; ++r)
                    sT[(mw + mi*16 + quad*4 + r)*137 + nw + nj*16 + l16] =
                        (_Float16)acc[mi][nj][r];
        __syncthreads();
        #pragma unroll
        for (int ii = 0; ii < 8; ++ii) {
            int u = tid + ii * 256;
            int dloc = u >> 4;          // 0..127
            int tch  = u & 15;          // consecutive lanes -> consecutive t
            hv8 o;
            #pragma unroll
            for (int j = 0; j < 8; ++j) o[j] = sT[(tch*8 + j)*137 + dloc];
            int gn = n0 + dloc;
            int hI = gn >> 6, dI = gn & 63;
            int gm = m0 + tch * 8;
            int bI = gm >> 10, tI = gm & 1023;
            *(hv8*)(Vt + (((size_t)bI * NH + hI) * HD + dI) * TT + tI) = o;
        }
    }
}

// ---------------------------------------------------------------------------
// fp16 single-pass output GEMM: out(fp32) = A @ BT^T + bias
// ---------------------------------------------------------------------------
__global__ __launch_bounds__(256) void gemm_out_f16(
    const _Float16* __restrict__ A, const _Float16* __restrict__ BT,
    const float* __restrict__ bias, float* __restrict__ out)
{
    __shared__ _Float16 sA[128][72];
    __shared__ _Float16 sB[128][72];

    const int tid  = threadIdx.x;
    const int wave = tid >> 6, lane = tid & 63;
    const int quad = lane >> 4, l16 = lane & 15;
    const int m0 = blockIdx.y * 128, n0 = blockIdx.x * 128;
    const int mw = (wave & 1) * 64, nw = (wave >> 1) * 64;

    f32x4 acc[4][4];
    #pragma unroll
    for (int i = 0; i < 4; ++i)
        #pragma unroll
        for (int j = 0; j < 4; ++j) acc[i][j] = (f32x4){0.f,0.f,0.f,0.f};

    for (int kt = 0; kt < CC; kt += 64) {
        #pragma unroll
        for (int ii = 0; ii < 4; ++ii) {
            int u = tid + ii * 256;
            int row = u >> 3, c8 = u & 7;
            *(short8*)&sA[row][c8*8] =
                *(const short8*)(A  + (size_t)(m0 + row) * CC + kt + c8*8);
            *(short8*)&sB[row][c8*8] =
                *(const short8*)(BT + (size_t)(n0 + row) * CC + kt + c8*8);
        }
        __syncthreads();
        #pragma unroll
        for (int kk = 0; kk < 2; ++kk) {
            hv8 af[4], bf[4];
            #pragma unroll
            for (int mi = 0; mi < 4; ++mi)
                af[mi] = *(const hv8*)&sA[mw + mi*16 + l16][kk*32 + quad*8];
            #pragma unroll
            for (int nj = 0; nj < 4; ++nj)
                bf[nj] = *(const hv8*)&sB[nw + nj*16 + l16][kk*32 + quad*8];
            #pragma unroll
            for (int mi = 0; mi < 4; ++mi)
                #pragma unroll
                for (int nj = 0; nj < 4; ++nj)
                    acc[mi][nj] = __builtin_amdgcn_mfma_f32_16x16x32_f16(
                        af[mi], bf[nj], acc[mi][nj], 0, 0, 0);
        }
        __syncthreads();
    }

    #pragma unroll
    for (int mi = 0; mi < 4; ++mi)
        #pragma unroll
        for (int nj = 0; nj < 4; ++nj)
            #pragma unroll
            for (int r = 0; r < 4; ++r) {
                int gm = m0 + mw + mi*16 + quad*4 + r;
                int gn = n0 + nw + nj*16 + l16;
                out[(size_t)gm * CC + gn] = acc[mi][nj][r] + bias[gn];
            }
}

// ---------------------------------------------------------------------------
// fp16 MFMA flash attention, BQ=128: 4 waves, each owns 32 q-rows (2 groups
// of 16).  K/V B-fragments reused across both groups -> ~1.7x less LDS
// traffic per MFMA.  K pre-scaled by 1/8.  V given transposed ([b,h,d,t]).
// LDS 45.6 KB -> 3 blocks/CU.
// ---------------------------------------------------------------------------
#define PW2 (32*72 + 8)   // per-wave sP region stride (halves)

__global__ __launch_bounds__(256) void attn_mfma(
    const _Float16* __restrict__ Q, const _Float16* __restrict__ K,
    const _Float16* __restrict__ Vt, const float* __restrict__ relh,
    const float* __restrict__ relw, _Float16* __restrict__ O)
{
    __shared__ _Float16 sK [64][72];   // loop: K tile | prologue: relh window (35 rows)
    __shared__ _Float16 sVt[64][72];   // loop: Vt tile | prologue: relw rows
    __shared__ _Float16 sP [4*PW2];    // loop: per-wave P (32x72) | prologue: Q (128x72) + G
    __shared__ _Float16 sH [128][34];  // rh table [qi][hk]

    const int tid  = threadIdx.x;
    const int wave = tid >> 6, lane = tid & 63;
    const int quad = lane >> 4, l16 = lane & 15;

    const int bid = blockIdx.x;
    const int qt  = bid & 7;           // 128-row q tile, 8 per head
    const int bh  = bid >> 3;
    const int h   = bh % NH;
    const int b   = bh / NH;
    const size_t hbase = ((size_t)b * NH + h) * TT * HD;

    // ---- prologue staging: Q (stride-72 overlay on sP), relh window, relw
    #pragma unroll
    for (int ii = 0; ii < 4; ++ii) {
        int u = tid + ii * 256;        // 0..1023
        int row = u >> 3, c8 = u & 7;
        *(short8*)&sP[row*72 + c8*8] =
            *(const short8*)(Q + hbase + (size_t)(qt*128 + row) * HD + c8*8);
    }
    #pragma unroll
    for (int ii = 0; ii < 2; ++ii) {
        int u = tid + ii * 256;
        if (u < 280) {                 // 35 rows x 8 chunks of relh window
            int row = u >> 3, c8 = u & 7;
            const float* src = relh + (size_t)(4*qt + row) * HD + c8*8;
            float4 v0 = *(const float4*)(src);
            float4 v1 = *(const float4*)(src + 4);
            hv8 s = { (_Float16)v0.x, (_Float16)v0.y, (_Float16)v0.z, (_Float16)v0.w,
                      (_Float16)v1.x, (_Float16)v1.y, (_Float16)v1.z, (_Float16)v1.w };
            *(hv8*)&sK[row][c8*8] = s;
        }
    }
    #pragma unroll
    for (int ii = 0; ii < 2; ++ii) {
        int u = tid + ii * 256;
        int row = u >> 3, c8 = u & 7;
        int sr = row < 63 ? row : 62;
        const float* src = relw + (size_t)sr * HD + c8*8;
        float4 v0 = *(const float4*)(src);
        float4 v1 = *(const float4*)(src + 4);
        hv8 s = { (_Float16)v0.x, (_Float16)v0.y, (_Float16)v0.z, (_Float16)v0.w,
                  (_Float16)v1.x, (_Float16)v1.y, (_Float16)v1.z, (_Float16)v1.w };
        *(hv8*)&sVt[row][c8*8] = s;
    }
    __syncthreads();

    // ---- persistent Q A-fragments (2 groups of 16 rows per wave)
    hv8 aQ0[2], aQ1[2];
    #pragma unroll
    for (int g = 0; g < 2; ++g) {
        int qrow = wave*32 + g*16 + l16;
        aQ0[g] = *(const hv8*)&sP[qrow*72 + quad*8];
        aQ1[g] = *(const hv8*)&sP[qrow*72 + 32 + quad*8];
    }
    __syncthreads();   // all aQ loaded before G-writes clobber the overlay

    // ---- RH via MFMA: sH[qi][hk] = q . relh[hq-hk+31]; hq = qt*4+wave
    #pragma unroll
    for (int g = 0; g < 2; ++g)
        #pragma unroll
        for (int t = 0; t < 2; ++t) {
            int wr = wave + 31 - (t*16 + l16);       // window row, in [wave, wave+31]
            hv8 b0 = *(const hv8*)&sK[wr][quad*8];
            hv8 b1 = *(const hv8*)&sK[wr][32 + quad*8];
            f32x4 c = {0.f,0.f,0.f,0.f};
            c = __builtin_amdgcn_mfma_f32_16x16x32_f16(aQ0[g], b0, c, 0, 0, 0);
            c = __builtin_amdgcn_mfma_f32_16x16x32_f16(aQ1[g], b1, c, 0, 0, 0);
            #pragma unroll
            for (int r = 0; r < 4; ++r)
                sH[wave*32 + g*16 + quad*4 + r][t*16 + l16] = (_Float16)c[r];
        }
    // ---- G = Q @ relw^T into own-wave sP region (col 63 garbage, unused)
    #pragma unroll
    for (int g = 0; g < 2; ++g)
        #pragma unroll
        for (int t = 0; t < 4; ++t) {
            hv8 b0 = *(const hv8*)&sVt[t*16 + l16][quad*8];
            hv8 b1 = *(const hv8*)&sVt[t*16 + l16][32 + quad*8];
            f32x4 c = {0.f,0.f,0.f,0.f};
            c = __builtin_amdgcn_mfma_f32_16x16x32_f16(aQ0[g], b0, c, 0, 0, 0);
            c = __builtin_amdgcn_mfma_f32_16x16x32_f16(aQ1[g], b1, c, 0, 0, 0);
            #pragma unroll
            for (int r = 0; r < 4; ++r)
                sP[wave*PW2 + (g*16 + quad*4 + r)*72 + t*16 + l16] = (_Float16)c[r];
        }
    // ---- gather RW bias (own wave region; lgkmcnt orders same-wave LDS)
    float rwReg[2][2][4];
    #pragma unroll
    for (int g = 0; g < 2; ++g)
        #pragma unroll
        for (int j = 0; j < 2; ++j)
            #pragma unroll
            for (int r = 0; r < 4; ++r) {
                int idx = g*16 + quad*4 + r - j*16 - l16 + 31;   // 0..62
                rwReg[g][j][r] = (float)sP[wave*PW2 + (g*16 + quad*4 + r)*72 + idx];
            }
    __syncthreads();

    f32x4 o[2][4];
    #pragma unroll
    for (int g = 0; g < 2; ++g)
        #pragma unroll
        for (int n = 0; n < 4; ++n) o[g][n] = (f32x4){0.f,0.f,0.f,0.f};
    float l[2][4] = {{0.f,0.f,0.f,0.f},{0.f,0.f,0.f,0.f}};

    for (int kt = 0; kt < 16; ++kt) {
        // ---- stage K [kj][d] and Vt [d][kj] tiles (all b128)
        #pragma unroll
        for (int ii = 0; ii < 2; ++ii) {
            int u = tid + ii * 256;
            int row = u >> 3, c8 = u & 7;
            *(short8*)&sK[row][c8*8] =
                *(const short8*)(K + hbase + (size_t)(kt*64 + row) * HD + c8*8);
            *(short8*)&sVt[row][c8*8] =
                *(const short8*)(Vt + hbase + (size_t)row * TT + kt*64 + c8*8);
        }
        __syncthreads();

        // ---- per-row RH bias for this k-tile (broadcast reads)
        float rh[2][2][4];
        #pragma unroll
        for (int g = 0; g < 2; ++g)
            #pragma unroll
            for (int t2 = 0; t2 < 2; ++t2)
                #pragma unroll
                for (int r = 0; r < 4; ++r)
                    rh[g][t2][r] = (float)sH[wave*32 + g*16 + quad*4 + r][kt*2 + t2];

        // ---- scores + exp + pack P  (bK frags shared across both groups)
        float rs[2][4] = {{0.f,0.f,0.f,0.f},{0.f,0.f,0.f,0.f}};
        #pragma unroll
        for (int bb = 0; bb < 4; ++bb) {
            hv8 bK0 = *(const hv8*)&sK[bb*16 + l16][quad*8];
            hv8 bK1 = *(const hv8*)&sK[bb*16 + l16][32 + quad*8];
            #pragma unroll
            for (int g = 0; g < 2; ++g) {
                f32x4 c = {0.f,0.f,0.f,0.f};
                c = __builtin_amdgcn_mfma_f32_16x16x32_f16(aQ0[g], bK0, c, 0, 0, 0);
                c = __builtin_amdgcn_mfma_f32_16x16x32_f16(aQ1[g], bK1, c, 0, 0, 0);
                #pragma unroll
                for (int r = 0; r < 4; ++r) {
                    float p = __expf(c[r] + rh[g][bb>>1][r] + rwReg[g][bb&1][r]);
                    rs[g][r] += p;
                    sP[wave*PW2 + (g*16 + quad*4 + r)*72 + bb*16 + l16] = (_Float16)p;
                }
            }
        }
        #pragma unroll
        for (int g = 0; g < 2; ++g)
            #pragma unroll
            for (int r = 0; r < 4; ++r) {
                float t = rs[g][r];
                t += __shfl_xor(t, 1);
                t += __shfl_xor(t, 2);
                t += __shfl_xor(t, 4);
                t += __shfl_xor(t, 8);
                l[g][r] += t;
            }

        // ---- O += P @ V  (bV frags shared across both groups)
        hv8 aP0[2], aP1[2];
        #pragma unroll
        for (int g = 0; g < 2; ++g) {
            aP0[g] = *(const hv8*)&sP[wave*PW2 + (g*16 + l16)*72 + quad*8];
            aP1[g] = *(const hv8*)&sP[wave*PW2 + (g*16 + l16)*72 + 32 + quad*8];
        }
        #pragma unroll
        for (int n = 0; n < 4; ++n) {
            hv8 bV0 = *(const hv8*)&sVt[n*16 + l16][quad*8];
            hv8 bV1 = *(const hv8*)&sVt[n*16 + l16][32 + quad*8];
            #pragma unroll
            for (int g = 0; g < 2; ++g) {
                o[g][n] = __builtin_amdgcn_mfma_f32_16x16x32_f16(aP0[g], bV0, o[g][n], 0, 0, 0);
                o[g][n] = __builtin_amdgcn_mfma_f32_16x16x32_f16(aP1[g], bV1, o[g][n], 0, 0, 0);
            }
        }
        __syncthreads();
    }

    // ---- finalize: /l, fp16 out into [b, t, C]
    #pragma unroll
    for (int g = 0; g < 2; ++g) {
        float inv[4];
        #pragma unroll
        for (int r = 0; r < 4; ++r) inv[r] = 1.f / l[g][r];
        #pragma unroll
        for (int n = 0; n < 4; ++n)
            #pragma unroll
            for (int r = 0; r < 4; ++r) {
                int t = qt*128 + wave*32 + g*16 + quad*4 + r;
                size_t addr = ((size_t)b * TT + t) * CC + h*HD + n*16 + l16;
                O[addr] = (_Float16)(o[g][n][r] * inv[r]);
            }
    }
}

// ---------------------------------------------------------------------------
extern "C" void kernel_launch(void* const* d_in, const int* in_sizes, int n_in,
                              void* d_out, int out_size, void* d_ws, size_t ws_size,
                              hipStream_t stream) {
    const float* x   = (const float*)d_in[0];
    const float* ctx = (const float*)d_in[1];
    const float* Wq  = (const float*)d_in[2];
    const float* Wk  = (const float*)d_in[3];
    const float* Wv  = (const float*)d_in[4];
    const float* Wo  = (const float*)d_in[5];
    const float* bo  = (const float*)d_in[6];
    const float* rh  = (const float*)d_in[7];
    const float* rw  = (const float*)d_in[8];
    float* out = (float*)d_out;

    const size_t MN = (size_t)BB * TT * CC;   // 6291456
    const size_t WN = (size_t)CC * CC;        // 589824
    _Float16* p = (_Float16*)d_ws;
    _Float16* xh  = p; p += MN;
    _Float16* ch  = p; p += MN;
    _Float16* WqT = p; p += WN;
    _Float16* WkT = p; p += WN;
    _Float16* WvT = p; p += WN;
    _Float16* WoT = p; p += WN;
    _Float16* Qh  = p; p += MN;
    _Float16* Kh  = p; p += MN;
    _Float16* VtB = p; p += MN;
    _Float16* Oh  = p; p += MN;

    dim3 blk(256);

    convert_f16x2<<<dim3(MN/2048, 1, 2), blk, 0, stream>>>(x, ctx, xh, ch, (int)MN);

    transpose_w4<<<dim3(12, 12, 4), blk, 0, stream>>>(
        Wq, Wk, Wv, Wo, WqT, WkT, WvT, WoT);

    gemm_qkv3<<<dim3(CC/128, (BB*TT)/128, 3), blk, 0, stream>>>(
        xh, ch, WqT, WkT, WvT, Qh, Kh, VtB);

    attn_mfma<<<dim3(BB*NH*(TT/128)), blk, 0, stream>>>(
        Qh, Kh, VtB, rh, rw, Oh);

    gemm_out_f16<<<dim3(CC/128, (BB*TT)/128), blk, 0, stream>>>(
        Oh, WoT, bo, out);
}